// Round 1
// baseline (234.051 us; speedup 1.0000x reference)
//
#include <hip/hip_runtime.h>
#include <hip/hip_bf16.h>

// ---------- helpers ----------
typedef __attribute__((ext_vector_type(4))) float f32x4;
typedef __attribute__((ext_vector_type(8))) short s16x8;

#define MFMA16(a, b, c) __builtin_amdgcn_mfma_f32_16x16x32_bf16(a, b, c, 0, 0, 0)

__device__ __forceinline__ void gld_lds16(const void* g, void* l) {
  __builtin_amdgcn_global_load_lds(
      (const __attribute__((address_space(1))) unsigned int*)g,
      (__attribute__((address_space(3))) unsigned int*)l, 16, 0, 0);
}

__device__ __forceinline__ unsigned short f2bf(float f) {
  union { __hip_bfloat16 b; unsigned short u; } cv;
  cv.b = __float2bfloat16(f);
  return cv.u;
}
__device__ __forceinline__ float bf2f(unsigned short u) {
  union { unsigned short u; __hip_bfloat16 b; } cv;
  cv.u = u;
  return __bfloat162float(cv.b);
}

// ---------- kernel 1: W [K][N] f32 -> W^T [N][K] split bf16 hi/lo ----------
__global__ void transw(const float* W0, unsigned short* H0, unsigned short* L0,
                       const float* W1, unsigned short* H1, unsigned short* L1,
                       const float* W2, unsigned short* H2, unsigned short* L2,
                       const float* W3, unsigned short* H3, unsigned short* L3) {
  __shared__ float tile[64 * 65];
  const float* W; unsigned short* H; unsigned short* L;
  switch (blockIdx.y) {
    case 0: W = W0; H = H0; L = L0; break;
    case 1: W = W1; H = H1; L = L1; break;
    case 2: W = W2; H = H2; L = L2; break;
    default: W = W3; H = H3; L = L3; break;
  }
  const int t = threadIdx.x;
  const int tk0 = (blockIdx.x & 15) * 64;   // k tile
  const int tn0 = (blockIdx.x >> 4) * 64;   // n tile
  for (int i = 0; i < 16; ++i) {
    int idx = i * 256 + t;
    int r = idx >> 6, c = idx & 63;
    tile[r * 65 + c] = W[(size_t)(tk0 + r) * 1024 + tn0 + c];
  }
  __syncthreads();
  for (int i = 0; i < 16; ++i) {
    int idx = i * 256 + t;
    int r = idx >> 6, c = idx & 63;   // r: n offset, c: k offset
    float v = tile[c * 65 + r];
    unsigned short hx = f2bf(v);
    unsigned short lx = f2bf(v - bf2f(hx));
    size_t off = (size_t)(tn0 + r) * 1024 + tk0 + c;
    H[off] = hx; L[off] = lx;
  }
}

// ---------- kernel 2: X [4096][1024] f32 -> split bf16 hi/lo ----------
__global__ void convert_x3(const float* A0, unsigned short* H0, unsigned short* L0,
                           const float* A1, unsigned short* H1, unsigned short* L1,
                           const float* A2, unsigned short* H2, unsigned short* L2) {
  const float* src; unsigned short* h; unsigned short* l;
  switch (blockIdx.y) {
    case 0: src = A0; h = H0; l = L0; break;
    case 1: src = A1; h = H1; l = L1; break;
    default: src = A2; h = H2; l = L2; break;
  }
  int i = blockIdx.x * 256 + threadIdx.x;   // float4 index, grid.x*256 == 1048576
  float4 v = ((const float4*)src)[i];
  unsigned short hx, hy, hz, hw;
  hx = f2bf(v.x); hy = f2bf(v.y); hz = f2bf(v.z); hw = f2bf(v.w);
  ushort4 hv = make_ushort4(hx, hy, hz, hw);
  ushort4 lv = make_ushort4(f2bf(v.x - bf2f(hx)), f2bf(v.y - bf2f(hy)),
                            f2bf(v.z - bf2f(hz)), f2bf(v.w - bf2f(hw)));
  ((ushort4*)h)[i] = hv;
  ((ushort4*)l)[i] = lv;
}

// ---------- kernel 3: split-bf16 GEMM, C = A[M,K] * B^T[N,K] + bias ----------
// MODE 0: write out[b][h][s][64] (QKV). MODE 1: write out[row][N] flat.
template <int MODE>
__global__ __launch_bounds__(256, 2)
void gemm_split(const unsigned short* __restrict__ Ahi, const unsigned short* __restrict__ Alo,
                const unsigned short* __restrict__ Bhi, const unsigned short* __restrict__ Blo,
                const float* __restrict__ bias, float* __restrict__ out) {
  const int K = 1024, N = 1024;
  __shared__ __align__(16) unsigned short lA[2][128 * 64];
  __shared__ __align__(16) unsigned short lB[2][128 * 64];
  const int tid = threadIdx.x;
  const int lane = tid & 63, wid = tid >> 6;
  const int m0 = blockIdx.y * 128, n0 = blockIdx.x * 128;
  const int wm = (wid >> 1) * 64, wn = (wid & 1) * 64;

  f32x4 acc[4][4] = {};

  const int srow = lane >> 3;          // row within 8-row segment
  const int scol = (lane & 7) * 8;     // k offset of this lane's 16B

  for (int kt = 0; kt < K; kt += 64) {
    #pragma unroll
    for (int i = 0; i < 4; ++i) {
      int s = wid * 4 + i;             // segment 0..15 (8 rows each)
      int row = s * 8 + srow;
      gld_lds16(Ahi + (size_t)(m0 + row) * K + kt + scol, &lA[0][s * 512]);
      gld_lds16(Alo + (size_t)(m0 + row) * K + kt + scol, &lA[1][s * 512]);
      gld_lds16(Bhi + (size_t)(n0 + row) * K + kt + scol, &lB[0][s * 512]);
      gld_lds16(Blo + (size_t)(n0 + row) * K + kt + scol, &lB[1][s * 512]);
    }
    asm volatile("s_waitcnt vmcnt(0)" ::: "memory");
    __syncthreads();

    #pragma unroll
    for (int kk = 0; kk < 64; kk += 32) {
      s16x8 ah[4], al[4], bh[4], bl[4];
      const int fr = lane & 15;
      const int fc = kk + ((lane >> 4) << 3);
      #pragma unroll
      for (int t = 0; t < 4; ++t) {
        int ar = wm + t * 16 + fr;
        ah[t] = *(const s16x8*)&lA[0][ar * 64 + fc];
        al[t] = *(const s16x8*)&lA[1][ar * 64 + fc];
        int br = wn + t * 16 + fr;
        bh[t] = *(const s16x8*)&lB[0][br * 64 + fc];
        bl[t] = *(const s16x8*)&lB[1][br * 64 + fc];
      }
      #pragma unroll
      for (int mt = 0; mt < 4; ++mt)
        #pragma unroll
        for (int nt = 0; nt < 4; ++nt) {
          acc[mt][nt] = MFMA16(ah[mt], bh[nt], acc[mt][nt]);
          acc[mt][nt] = MFMA16(ah[mt], bl[nt], acc[mt][nt]);
          acc[mt][nt] = MFMA16(al[mt], bh[nt], acc[mt][nt]);
        }
    }
    __syncthreads();
  }

  // epilogue: C/D layout col = lane&15, row = (lane>>4)*4 + j  [verified m89/m91]
  #pragma unroll
  for (int mt = 0; mt < 4; ++mt) {
    #pragma unroll
    for (int nt = 0; nt < 4; ++nt) {
      const int gm = m0 + wm + mt * 16 + ((lane >> 4) << 2);
      const int gn = n0 + wn + nt * 16 + (lane & 15);
      const float bv = bias[gn];
      f32x4 r = acc[mt][nt];
      #pragma unroll
      for (int j = 0; j < 4; ++j) {
        int row = gm + j;
        float val = r[j] + bv;
        if (MODE == 0) {
          // [b*16+h][s][d]: b=row>>11, s=row&2047, h=gn>>6, d=gn&63
          size_t off = (((size_t)((row >> 11) * 16 + (gn >> 6))) * 2048 + (row & 2047)) * 64 + (gn & 63);
          out[off] = val;
        } else {
          out[(size_t)row * N + gn] = val;
        }
      }
    }
  }
}

// ---------- kernel 4: block-diagonal attention, f32 core ----------
// grid.x = 1024 = (b*16+h)*32 + qblock. Q/K/V are [32][2048][64] f32.
// Emits x as split bf16 hi/lo in [b*2048+s][h*64+d] layout for the O-proj GEMM.
__global__ __launch_bounds__(256, 3)
void attn_block(const float* __restrict__ Q, const float* __restrict__ Kt,
                const float* __restrict__ V,
                unsigned short* __restrict__ Xhi, unsigned short* __restrict__ Xlo) {
  __shared__ __align__(16) float qs[64 * 68];   // q rows; reused for P (row-partitioned per wave)
  __shared__ __align__(16) float ks[64 * 65];
  __shared__ __align__(16) float vs[64 * 65];
  const int tid = threadIdx.x;
  const int lane = tid & 63, w = tid >> 6;
  const int hb = blockIdx.x >> 5;   // b*16 + h  (0..31)
  const int qb = blockIdx.x & 31;   // q block   (0..31)
  const size_t base = ((size_t)hb * 2048 + qb * 64) * 64;

  for (int i = 0; i < 4; ++i) {
    int idx = i * 256 + tid;            // float4 unit 0..1023
    int row = idx >> 4, c4 = (idx & 15) * 4;
    float4 qv = *(const float4*)&Q[base + (size_t)row * 64 + c4];
    float4 kv = *(const float4*)&Kt[base + (size_t)row * 64 + c4];
    float4 vv = *(const float4*)&V[base + (size_t)row * 64 + c4];
    *(float4*)&qs[row * 68 + c4] = qv;
    ks[row * 65 + c4 + 0] = kv.x; ks[row * 65 + c4 + 1] = kv.y;
    ks[row * 65 + c4 + 2] = kv.z; ks[row * 65 + c4 + 3] = kv.w;
    vs[row * 65 + c4 + 0] = vv.x; vs[row * 65 + c4 + 1] = vv.y;
    vs[row * 65 + c4 + 2] = vv.z; vs[row * 65 + c4 + 3] = vv.w;
  }
  __syncthreads();

  // scores: lane = key index c; this wave owns q rows [w*16, w*16+16)
  float sc[16];
  #pragma unroll
  for (int r = 0; r < 16; ++r) sc[r] = 0.f;
  for (int d4 = 0; d4 < 64; d4 += 4) {
    float k0 = ks[lane * 65 + d4 + 0], k1 = ks[lane * 65 + d4 + 1];
    float k2 = ks[lane * 65 + d4 + 2], k3 = ks[lane * 65 + d4 + 3];
    #pragma unroll
    for (int r = 0; r < 16; ++r) {
      const float4 qv = *(const float4*)&qs[(w * 16 + r) * 68 + d4];
      sc[r] += qv.x * k0 + qv.y * k1 + qv.z * k2 + qv.w * k3;
    }
  }
  // wave-wide softmax per row (64 keys spread across 64 lanes)
  #pragma unroll
  for (int r = 0; r < 16; ++r) {
    float s = sc[r] * 0.125f;           // 1/sqrt(64)
    float m = s;
    #pragma unroll
    for (int off = 32; off > 0; off >>= 1) m = fmaxf(m, __shfl_xor(m, off, 64));
    float p = __expf(s - m);
    float sum = p;
    #pragma unroll
    for (int off = 32; off > 0; off >>= 1) sum += __shfl_xor(sum, off, 64);
    sc[r] = p / sum;
  }
  // park P in qs (each wave writes only its own 16 rows; no cross-wave readers)
  #pragma unroll
  for (int r = 0; r < 16; ++r) qs[(w * 16 + r) * 68 + lane] = sc[r];

  // PV: lane = output dim d
  float xa[16];
  #pragma unroll
  for (int r = 0; r < 16; ++r) xa[r] = 0.f;
  for (int c4 = 0; c4 < 64; c4 += 4) {
    float v0 = vs[(c4 + 0) * 65 + lane], v1 = vs[(c4 + 1) * 65 + lane];
    float v2 = vs[(c4 + 2) * 65 + lane], v3 = vs[(c4 + 3) * 65 + lane];
    #pragma unroll
    for (int r = 0; r < 16; ++r) {
      const float4 pv = *(const float4*)&qs[(w * 16 + r) * 68 + c4];
      xa[r] += pv.x * v0 + pv.y * v1 + pv.z * v2 + pv.w * v3;
    }
  }
  const int b = hb >> 4, h = hb & 15;
  #pragma unroll
  for (int r = 0; r < 16; ++r) {
    float val = xa[r];
    unsigned short hx = f2bf(val);
    unsigned short lx = f2bf(val - bf2f(hx));
    size_t off = ((size_t)(b * 2048 + qb * 64 + w * 16 + r)) * 1024 + h * 64 + lane;
    Xhi[off] = hx; Xlo[off] = lx;
  }
}

// ---------- launch ----------
extern "C" void kernel_launch(void* const* d_in, const int* in_sizes, int n_in,
                              void* d_out, int out_size, void* d_ws, size_t ws_size,
                              hipStream_t stream) {
  const float* query = (const float*)d_in[0];
  const float* key   = (const float*)d_in[1];
  const float* value = (const float*)d_in[2];
  const float* Wq = (const float*)d_in[3]; const float* bq = (const float*)d_in[4];
  const float* Wk = (const float*)d_in[5]; const float* bk = (const float*)d_in[6];
  const float* Wv = (const float*)d_in[7]; const float* bv = (const float*)d_in[8];
  const float* Wo = (const float*)d_in[9]; const float* bo = (const float*)d_in[10];
  float* out = (float*)d_out;

  const size_t W_E = 1024 * 1024;            // weight elements
  const size_t X_E = 4096 * 1024;            // activation elements
  unsigned char* p = (unsigned char*)d_ws;
  auto take = [&](size_t bytes) { void* r = (void*)p; p += bytes; return r; };

  unsigned short* wtq_hi = (unsigned short*)take(W_E * 2);
  unsigned short* wtq_lo = (unsigned short*)take(W_E * 2);
  unsigned short* wtk_hi = (unsigned short*)take(W_E * 2);
  unsigned short* wtk_lo = (unsigned short*)take(W_E * 2);
  unsigned short* wtv_hi = (unsigned short*)take(W_E * 2);
  unsigned short* wtv_lo = (unsigned short*)take(W_E * 2);
  unsigned short* wto_hi = (unsigned short*)take(W_E * 2);
  unsigned short* wto_lo = (unsigned short*)take(W_E * 2);
  unsigned short* xq_hi = (unsigned short*)take(X_E * 2);
  unsigned short* xq_lo = (unsigned short*)take(X_E * 2);
  unsigned short* xk_hi = (unsigned short*)take(X_E * 2);
  unsigned short* xk_lo = (unsigned short*)take(X_E * 2);
  unsigned short* xv_hi = (unsigned short*)take(X_E * 2);
  unsigned short* xv_lo = (unsigned short*)take(X_E * 2);
  float* Qf = (float*)take(X_E * 4);
  float* Kf = (float*)take(X_E * 4);
  float* Vf = (float*)take(X_E * 4);
  unsigned short* ao_hi = (unsigned short*)take(X_E * 2);
  unsigned short* ao_lo = (unsigned short*)take(X_E * 2);
  (void)ws_size; (void)in_sizes; (void)n_in; (void)out_size;

  // 1. weights -> transposed split-bf16
  transw<<<dim3(256, 4), 256, 0, stream>>>(Wq, wtq_hi, wtq_lo, Wk, wtk_hi, wtk_lo,
                                           Wv, wtv_hi, wtv_lo, Wo, wto_hi, wto_lo);
  // 2. activations -> split-bf16
  convert_x3<<<dim3(4096, 3), 256, 0, stream>>>(query, xq_hi, xq_lo,
                                                key, xk_hi, xk_lo,
                                                value, xv_hi, xv_lo);
  // 3. projections (f32-accurate 3-term MFMA), outputs in [b,h,s,dk] f32
  gemm_split<0><<<dim3(8, 32), 256, 0, stream>>>(xq_hi, xq_lo, wtq_hi, wtq_lo, bq, Qf);
  gemm_split<0><<<dim3(8, 32), 256, 0, stream>>>(xk_hi, xk_lo, wtk_hi, wtk_lo, bk, Kf);
  gemm_split<0><<<dim3(8, 32), 256, 0, stream>>>(xv_hi, xv_lo, wtv_hi, wtv_lo, bv, Vf);
  // 4. block-diagonal attention (f32 core), emits split-bf16 x
  attn_block<<<dim3(1024), 256, 0, stream>>>(Qf, Kf, Vf, ao_hi, ao_lo);
  // 5. output projection -> f32 d_out
  gemm_split<1><<<dim3(8, 32), 256, 0, stream>>>(ao_hi, ao_lo, wto_hi, wto_lo, bo, out);
}

// Round 2
// 195.624 us; speedup vs baseline: 1.1964x; 1.1964x over previous
//
#include <hip/hip_runtime.h>
#include <hip/hip_bf16.h>

// ---------- helpers ----------
typedef __attribute__((ext_vector_type(4))) float f32x4;
typedef __attribute__((ext_vector_type(8))) short s16x8;

#define MFMA16(a, b, c) __builtin_amdgcn_mfma_f32_16x16x32_bf16(a, b, c, 0, 0, 0)

__device__ __forceinline__ void gld_lds16(const void* g, void* l) {
  __builtin_amdgcn_global_load_lds(
      (const __attribute__((address_space(1))) unsigned int*)g,
      (__attribute__((address_space(3))) unsigned int*)l, 16, 0, 0);
}

__device__ __forceinline__ unsigned short f2bf(float f) {
  union { __hip_bfloat16 b; unsigned short u; } cv;
  cv.b = __float2bfloat16(f);
  return cv.u;
}
__device__ __forceinline__ float bf2f(unsigned short u) {
  union { unsigned short u; __hip_bfloat16 b; } cv;
  cv.u = u;
  return __bfloat162float(cv.b);
}

// ---------- kernel 1: W [K][N] f32 -> W^T [N][K] split bf16 hi/lo ----------
__global__ void transw(const float* W0, unsigned short* H0, unsigned short* L0,
                       const float* W1, unsigned short* H1, unsigned short* L1,
                       const float* W2, unsigned short* H2, unsigned short* L2,
                       const float* W3, unsigned short* H3, unsigned short* L3) {
  __shared__ float tile[64 * 65];
  const float* W; unsigned short* H; unsigned short* L;
  switch (blockIdx.y) {
    case 0: W = W0; H = H0; L = L0; break;
    case 1: W = W1; H = H1; L = L1; break;
    case 2: W = W2; H = H2; L = L2; break;
    default: W = W3; H = H3; L = L3; break;
  }
  const int t = threadIdx.x;
  const int tk0 = (blockIdx.x & 15) * 64;   // k tile
  const int tn0 = (blockIdx.x >> 4) * 64;   // n tile
  for (int i = 0; i < 16; ++i) {
    int idx = i * 256 + t;
    int r = idx >> 6, c = idx & 63;
    tile[r * 65 + c] = W[(size_t)(tk0 + r) * 1024 + tn0 + c];
  }
  __syncthreads();
  for (int i = 0; i < 16; ++i) {
    int idx = i * 256 + t;
    int r = idx >> 6, c = idx & 63;   // r: n offset, c: k offset
    float v = tile[c * 65 + r];
    unsigned short hx = f2bf(v);
    unsigned short lx = f2bf(v - bf2f(hx));
    size_t off = (size_t)(tn0 + r) * 1024 + tk0 + c;
    H[off] = hx; L[off] = lx;
  }
}

// ---------- kernel 2: X [4096][1024] f32 -> split bf16 hi/lo ----------
__global__ void convert_x3(const float* A0, unsigned short* H0, unsigned short* L0,
                           const float* A1, unsigned short* H1, unsigned short* L1,
                           const float* A2, unsigned short* H2, unsigned short* L2) {
  const float* src; unsigned short* h; unsigned short* l;
  switch (blockIdx.y) {
    case 0: src = A0; h = H0; l = L0; break;
    case 1: src = A1; h = H1; l = L1; break;
    default: src = A2; h = H2; l = L2; break;
  }
  int i = blockIdx.x * 256 + threadIdx.x;   // float4 index, grid.x*256 == 1048576
  float4 v = ((const float4*)src)[i];
  unsigned short hx, hy, hz, hw;
  hx = f2bf(v.x); hy = f2bf(v.y); hz = f2bf(v.z); hw = f2bf(v.w);
  ushort4 hv = make_ushort4(hx, hy, hz, hw);
  ushort4 lv = make_ushort4(f2bf(v.x - bf2f(hx)), f2bf(v.y - bf2f(hy)),
                            f2bf(v.z - bf2f(hz)), f2bf(v.w - bf2f(hw)));
  ((ushort4*)h)[i] = hv;
  ((ushort4*)l)[i] = lv;
}

// ---------- kernel 3: split-bf16 GEMM, C = A[M,K] * B^T[N,K] + bias ----------
// Up to NG independent GEMMs batched in one launch (grid.x = NG*256).
// Tile 128x128, BK=32, double-buffered LDS, XOR-swizzled granules.
// LDS row layout: row r holds 8 granules of 16B; granule g' at byte g'*16 stores
// global granule g = g' ^ (r&7); g<4 -> hi k-bytes [g*16,+16), g>=4 -> lo [(g-4)*16,+16).
// MODE 0: write out[b][h][s][64] (QKV). MODE 1: write out[row][N] flat.
struct GemmArgs {
  const unsigned short* Ahi[3]; const unsigned short* Alo[3];
  const unsigned short* Bhi[3]; const unsigned short* Blo[3];
  const float* bias[3];
  float* out[3];
};

template <int MODE, int NG>
__global__ __launch_bounds__(256, 2)
void gemm_split(GemmArgs args) {
  const int K = 1024, N = 1024;
  __shared__ __align__(16) unsigned short lA[2][128 * 64];
  __shared__ __align__(16) unsigned short lB[2][128 * 64];
  const int tid = threadIdx.x;
  const int lane = tid & 63, wid = tid >> 6;

  // XCD-aware bijective swizzle (nwg % 8 == 0), then decode (gemm g, m0, n0)
  const int nwg = NG * 256;
  const int orig = blockIdx.x;
  const int swz = (orig & 7) * (nwg >> 3) + (orig >> 3);
  const int g = swz >> 8;
  const int tl = swz & 255;
  const int m0 = (tl >> 3) * 128, n0 = (tl & 7) * 128;

  const unsigned short* Ahi = args.Ahi[g]; const unsigned short* Alo = args.Alo[g];
  const unsigned short* Bhi = args.Bhi[g]; const unsigned short* Blo = args.Blo[g];
  const float* bias = args.bias[g];
  float* out = args.out[g];

  const int wm = (wid >> 1) * 64, wn = (wid & 1) * 64;

  // --- staging source pointers (per-lane, inverse-swizzled so LDS dest is linear)
  // lane l writes linear LDS byte (seg*1024 + l*16): row = seg*8 + (l>>3), granule l&7.
  // stored granule (l&7) must hold global granule sp = (l&7) ^ (l>>3).
  const int sp = (lane & 7) ^ (lane >> 3);
  const int koff = (sp & 3) * 8;                 // k offset in shorts within the 32-k tile
  const unsigned short* aSrc[4]; const unsigned short* bSrc[4];
  #pragma unroll
  for (int i = 0; i < 4; ++i) {
    const int seg = wid * 4 + i;
    const int rA = m0 + seg * 8 + (lane >> 3);
    const int rB = n0 + seg * 8 + (lane >> 3);
    aSrc[i] = (sp < 4 ? Ahi : Alo) + (size_t)rA * K + koff;
    bSrc[i] = (sp < 4 ? Bhi : Blo) + (size_t)rB * K + koff;
  }

  f32x4 acc[4][4] = {};

  auto stage = [&](int buf, int kt) {
    #pragma unroll
    for (int i = 0; i < 4; ++i) {
      const int seg = wid * 4 + i;
      gld_lds16(aSrc[i] + kt, &lA[buf][seg * 512]);
      gld_lds16(bSrc[i] + kt, &lB[buf][seg * 512]);
    }
  };

  const int fr = lane & 15;
  const int gh = lane >> 4;   // hi granule index 0..3 for this lane's k-slot

  auto compute = [&](int buf) {
    s16x8 ah[4], al[4], bh[4], bl[4];
    #pragma unroll
    for (int t = 0; t < 4; ++t) {
      const int ar = wm + t * 16 + fr, ax = ar & 7;
      ah[t] = *(const s16x8*)&lA[buf][ar * 64 + ((gh ^ ax) << 3)];
      al[t] = *(const s16x8*)&lA[buf][ar * 64 + (((4 | gh) ^ ax) << 3)];
      const int br = wn + t * 16 + fr, bx = br & 7;
      bh[t] = *(const s16x8*)&lB[buf][br * 64 + ((gh ^ bx) << 3)];
      bl[t] = *(const s16x8*)&lB[buf][br * 64 + (((4 | gh) ^ bx) << 3)];
    }
    #pragma unroll
    for (int mt = 0; mt < 4; ++mt)
      #pragma unroll
      for (int nt = 0; nt < 4; ++nt) {
        acc[mt][nt] = MFMA16(ah[mt], bh[nt], acc[mt][nt]);
        acc[mt][nt] = MFMA16(ah[mt], bl[nt], acc[mt][nt]);
        acc[mt][nt] = MFMA16(al[mt], bh[nt], acc[mt][nt]);
      }
  };

  // --- 2-phase pipelined K loop: stage(next) issued before compute(cur)
  stage(0, 0);
  __syncthreads();
  #pragma unroll 1
  for (int kt2 = 0; kt2 < K; kt2 += 64) {
    stage(1, kt2 + 32);          // kt2+32 < K always (K=1024, kt2<=960)
    compute(0);
    __syncthreads();
    if (kt2 + 64 < K) stage(0, kt2 + 64);
    compute(1);
    __syncthreads();
  }

  // epilogue: C/D layout col = lane&15, row = (lane>>4)*4 + j  [verified m89/m91]
  #pragma unroll
  for (int mt = 0; mt < 4; ++mt) {
    #pragma unroll
    for (int nt = 0; nt < 4; ++nt) {
      const int gm = m0 + wm + mt * 16 + ((lane >> 4) << 2);
      const int gn = n0 + wn + nt * 16 + (lane & 15);
      const float bv = bias[gn];
      f32x4 r = acc[mt][nt];
      #pragma unroll
      for (int j = 0; j < 4; ++j) {
        int row = gm + j;
        float val = r[j] + bv;
        if (MODE == 0) {
          // [b*16+h][s][d]: b=row>>11, s=row&2047, h=gn>>6, d=gn&63
          size_t off = (((size_t)((row >> 11) * 16 + (gn >> 6))) * 2048 + (row & 2047)) * 64 + (gn & 63);
          out[off] = val;
        } else {
          out[(size_t)row * N + gn] = val;
        }
      }
    }
  }
}

// ---------- kernel 4: block-diagonal attention, f32 core ----------
// grid.x = 1024 = (b*16+h)*32 + qblock. Q/K/V are [32][2048][64] f32.
// Emits x as split bf16 hi/lo in [b*2048+s][h*64+d] layout for the O-proj GEMM.
__global__ __launch_bounds__(256, 3)
void attn_block(const float* __restrict__ Q, const float* __restrict__ Kt,
                const float* __restrict__ V,
                unsigned short* __restrict__ Xhi, unsigned short* __restrict__ Xlo) {
  __shared__ __align__(16) float qs[64 * 68];   // q rows; reused for P (row-partitioned per wave)
  __shared__ __align__(16) float ks[64 * 65];
  __shared__ __align__(16) float vs[64 * 65];
  const int tid = threadIdx.x;
  const int lane = tid & 63, w = tid >> 6;
  const int hb = blockIdx.x >> 5;   // b*16 + h  (0..31)
  const int qb = blockIdx.x & 31;   // q block   (0..31)
  const size_t base = ((size_t)hb * 2048 + qb * 64) * 64;

  for (int i = 0; i < 4; ++i) {
    int idx = i * 256 + tid;            // float4 unit 0..1023
    int row = idx >> 4, c4 = (idx & 15) * 4;
    float4 qv = *(const float4*)&Q[base + (size_t)row * 64 + c4];
    float4 kv = *(const float4*)&Kt[base + (size_t)row * 64 + c4];
    float4 vv = *(const float4*)&V[base + (size_t)row * 64 + c4];
    *(float4*)&qs[row * 68 + c4] = qv;
    ks[row * 65 + c4 + 0] = kv.x; ks[row * 65 + c4 + 1] = kv.y;
    ks[row * 65 + c4 + 2] = kv.z; ks[row * 65 + c4 + 3] = kv.w;
    vs[row * 65 + c4 + 0] = vv.x; vs[row * 65 + c4 + 1] = vv.y;
    vs[row * 65 + c4 + 2] = vv.z; vs[row * 65 + c4 + 3] = vv.w;
  }
  __syncthreads();

  // scores: lane = key index c; this wave owns q rows [w*16, w*16+16)
  float sc[16];
  #pragma unroll
  for (int r = 0; r < 16; ++r) sc[r] = 0.f;
  for (int d4 = 0; d4 < 64; d4 += 4) {
    float k0 = ks[lane * 65 + d4 + 0], k1 = ks[lane * 65 + d4 + 1];
    float k2 = ks[lane * 65 + d4 + 2], k3 = ks[lane * 65 + d4 + 3];
    #pragma unroll
    for (int r = 0; r < 16; ++r) {
      const float4 qv = *(const float4*)&qs[(w * 16 + r) * 68 + d4];
      sc[r] += qv.x * k0 + qv.y * k1 + qv.z * k2 + qv.w * k3;
    }
  }
  // wave-wide softmax per row (64 keys spread across 64 lanes)
  #pragma unroll
  for (int r = 0; r < 16; ++r) {
    float s = sc[r] * 0.125f;           // 1/sqrt(64)
    float m = s;
    #pragma unroll
    for (int off = 32; off > 0; off >>= 1) m = fmaxf(m, __shfl_xor(m, off, 64));
    float p = __expf(s - m);
    float sum = p;
    #pragma unroll
    for (int off = 32; off > 0; off >>= 1) sum += __shfl_xor(sum, off, 64);
    sc[r] = p / sum;
  }
  // park P in qs (each wave writes only its own 16 rows; no cross-wave readers)
  #pragma unroll
  for (int r = 0; r < 16; ++r) qs[(w * 16 + r) * 68 + lane] = sc[r];

  // PV: lane = output dim d
  float xa[16];
  #pragma unroll
  for (int r = 0; r < 16; ++r) xa[r] = 0.f;
  for (int c4 = 0; c4 < 64; c4 += 4) {
    float v0 = vs[(c4 + 0) * 65 + lane], v1 = vs[(c4 + 1) * 65 + lane];
    float v2 = vs[(c4 + 2) * 65 + lane], v3 = vs[(c4 + 3) * 65 + lane];
    #pragma unroll
    for (int r = 0; r < 16; ++r) {
      const float4 pv = *(const float4*)&qs[(w * 16 + r) * 68 + c4];
      xa[r] += pv.x * v0 + pv.y * v1 + pv.z * v2 + pv.w * v3;
    }
  }
  const int b = hb >> 4, h = hb & 15;
  #pragma unroll
  for (int r = 0; r < 16; ++r) {
    float val = xa[r];
    unsigned short hx = f2bf(val);
    unsigned short lx = f2bf(val - bf2f(hx));
    size_t off = ((size_t)(b * 2048 + qb * 64 + w * 16 + r)) * 1024 + h * 64 + lane;
    Xhi[off] = hx; Xlo[off] = lx;
  }
}

// ---------- launch ----------
extern "C" void kernel_launch(void* const* d_in, const int* in_sizes, int n_in,
                              void* d_out, int out_size, void* d_ws, size_t ws_size,
                              hipStream_t stream) {
  const float* query = (const float*)d_in[0];
  const float* key   = (const float*)d_in[1];
  const float* value = (const float*)d_in[2];
  const float* Wq = (const float*)d_in[3]; const float* bq = (const float*)d_in[4];
  const float* Wk = (const float*)d_in[5]; const float* bk = (const float*)d_in[6];
  const float* Wv = (const float*)d_in[7]; const float* bv = (const float*)d_in[8];
  const float* Wo = (const float*)d_in[9]; const float* bo = (const float*)d_in[10];
  float* out = (float*)d_out;

  const size_t W_E = 1024 * 1024;            // weight elements
  const size_t X_E = 4096 * 1024;            // activation elements
  unsigned char* p = (unsigned char*)d_ws;
  auto take = [&](size_t bytes) { void* r = (void*)p; p += bytes; return r; };

  unsigned short* wtq_hi = (unsigned short*)take(W_E * 2);
  unsigned short* wtq_lo = (unsigned short*)take(W_E * 2);
  unsigned short* wtk_hi = (unsigned short*)take(W_E * 2);
  unsigned short* wtk_lo = (unsigned short*)take(W_E * 2);
  unsigned short* wtv_hi = (unsigned short*)take(W_E * 2);
  unsigned short* wtv_lo = (unsigned short*)take(W_E * 2);
  unsigned short* wto_hi = (unsigned short*)take(W_E * 2);
  unsigned short* wto_lo = (unsigned short*)take(W_E * 2);
  unsigned short* xq_hi = (unsigned short*)take(X_E * 2);
  unsigned short* xq_lo = (unsigned short*)take(X_E * 2);
  unsigned short* xk_hi = (unsigned short*)take(X_E * 2);
  unsigned short* xk_lo = (unsigned short*)take(X_E * 2);
  unsigned short* xv_hi = (unsigned short*)take(X_E * 2);
  unsigned short* xv_lo = (unsigned short*)take(X_E * 2);
  float* Qf = (float*)take(X_E * 4);
  float* Kf = (float*)take(X_E * 4);
  float* Vf = (float*)take(X_E * 4);
  unsigned short* ao_hi = (unsigned short*)take(X_E * 2);
  unsigned short* ao_lo = (unsigned short*)take(X_E * 2);
  (void)ws_size; (void)in_sizes; (void)n_in; (void)out_size;

  // 1. weights -> transposed split-bf16
  transw<<<dim3(256, 4), 256, 0, stream>>>(Wq, wtq_hi, wtq_lo, Wk, wtk_hi, wtk_lo,
                                           Wv, wtv_hi, wtv_lo, Wo, wto_hi, wto_lo);
  // 2. activations -> split-bf16
  convert_x3<<<dim3(4096, 3), 256, 0, stream>>>(query, xq_hi, xq_lo,
                                                key, xk_hi, xk_lo,
                                                value, xv_hi, xv_lo);
  // 3. Q,K,V projections batched in ONE launch (768 blocks, 2 resident/CU)
  GemmArgs qkv = {};
  qkv.Ahi[0] = xq_hi; qkv.Alo[0] = xq_lo; qkv.Bhi[0] = wtq_hi; qkv.Blo[0] = wtq_lo;
  qkv.bias[0] = bq;   qkv.out[0] = Qf;
  qkv.Ahi[1] = xk_hi; qkv.Alo[1] = xk_lo; qkv.Bhi[1] = wtk_hi; qkv.Blo[1] = wtk_lo;
  qkv.bias[1] = bk;   qkv.out[1] = Kf;
  qkv.Ahi[2] = xv_hi; qkv.Alo[2] = xv_lo; qkv.Bhi[2] = wtv_hi; qkv.Blo[2] = wtv_lo;
  qkv.bias[2] = bv;   qkv.out[2] = Vf;
  gemm_split<0, 3><<<dim3(768), 256, 0, stream>>>(qkv);
  // 4. block-diagonal attention (f32 core), emits split-bf16 x
  attn_block<<<dim3(1024), 256, 0, stream>>>(Qf, Kf, Vf, ao_hi, ao_lo);
  // 5. output projection -> f32 d_out
  GemmArgs og = {};
  og.Ahi[0] = ao_hi; og.Alo[0] = ao_lo; og.Bhi[0] = wto_hi; og.Blo[0] = wto_lo;
  og.bias[0] = bo;   og.out[0] = out;
  gemm_split<1, 1><<<dim3(256), 256, 0, stream>>>(og);
}

// Round 3
// 183.545 us; speedup vs baseline: 1.2752x; 1.0658x over previous
//
#include <hip/hip_runtime.h>
#include <hip/hip_bf16.h>

// ---------- helpers ----------
typedef __attribute__((ext_vector_type(4))) float f32x4;
typedef __attribute__((ext_vector_type(8))) short s16x8;

#define MFMA16(a, b, c) __builtin_amdgcn_mfma_f32_16x16x32_bf16(a, b, c, 0, 0, 0)

__device__ __forceinline__ void gld_lds16(const void* g, void* l) {
  __builtin_amdgcn_global_load_lds(
      (const __attribute__((address_space(1))) unsigned int*)g,
      (__attribute__((address_space(3))) unsigned int*)l, 16, 0, 0);
}

__device__ __forceinline__ unsigned short f2bf(float f) {
  union { __hip_bfloat16 b; unsigned short u; } cv;
  cv.b = __float2bfloat16(f);
  return cv.u;
}
__device__ __forceinline__ float bf2f(unsigned short u) {
  union { unsigned short u; __hip_bfloat16 b; } cv;
  cv.u = u;
  return __bfloat162float(cv.b);
}

// ---------- kernel 1: W [K][N] f32 -> W^T [N][K] split bf16 hi/lo ----------
__global__ void transw(const float* W0, unsigned short* H0, unsigned short* L0,
                       const float* W1, unsigned short* H1, unsigned short* L1,
                       const float* W2, unsigned short* H2, unsigned short* L2,
                       const float* W3, unsigned short* H3, unsigned short* L3) {
  __shared__ float tile[64 * 65];
  const float* W; unsigned short* H; unsigned short* L;
  switch (blockIdx.y) {
    case 0: W = W0; H = H0; L = L0; break;
    case 1: W = W1; H = H1; L = L1; break;
    case 2: W = W2; H = H2; L = L2; break;
    default: W = W3; H = H3; L = L3; break;
  }
  const int t = threadIdx.x;
  const int tk0 = (blockIdx.x & 15) * 64;   // k tile
  const int tn0 = (blockIdx.x >> 4) * 64;   // n tile
  for (int i = 0; i < 16; ++i) {
    int idx = i * 256 + t;
    int r = idx >> 6, c = idx & 63;
    tile[r * 65 + c] = W[(size_t)(tk0 + r) * 1024 + tn0 + c];
  }
  __syncthreads();
  for (int i = 0; i < 16; ++i) {
    int idx = i * 256 + t;
    int r = idx >> 6, c = idx & 63;   // r: n offset, c: k offset
    float v = tile[c * 65 + r];
    unsigned short hx = f2bf(v);
    unsigned short lx = f2bf(v - bf2f(hx));
    size_t off = (size_t)(tn0 + r) * 1024 + tk0 + c;
    H[off] = hx; L[off] = lx;
  }
}

// ---------- kernel 2: X [4096][1024] f32 -> split bf16 hi/lo ----------
__global__ void convert_x3(const float* A0, unsigned short* H0, unsigned short* L0,
                           const float* A1, unsigned short* H1, unsigned short* L1,
                           const float* A2, unsigned short* H2, unsigned short* L2) {
  const float* src; unsigned short* h; unsigned short* l;
  switch (blockIdx.y) {
    case 0: src = A0; h = H0; l = L0; break;
    case 1: src = A1; h = H1; l = L1; break;
    default: src = A2; h = H2; l = L2; break;
  }
  int i = blockIdx.x * 256 + threadIdx.x;   // float4 index, grid.x*256 == 1048576
  float4 v = ((const float4*)src)[i];
  unsigned short hx, hy, hz, hw;
  hx = f2bf(v.x); hy = f2bf(v.y); hz = f2bf(v.z); hw = f2bf(v.w);
  ushort4 hv = make_ushort4(hx, hy, hz, hw);
  ushort4 lv = make_ushort4(f2bf(v.x - bf2f(hx)), f2bf(v.y - bf2f(hy)),
                            f2bf(v.z - bf2f(hz)), f2bf(v.w - bf2f(hw)));
  ((ushort4*)h)[i] = hv;
  ((ushort4*)l)[i] = lv;
}

struct GemmArgs {
  const unsigned short* Ahi[3]; const unsigned short* Alo[3];
  const unsigned short* Bhi[3]; const unsigned short* Blo[3];
  const float* bias[3];
  float* out[3];
};

// ---------- kernel 3a: 256x256 8-wave phase-split GEMM (QKV) ----------
// C = A[M,K] * B^T[N,K] + bias, split-bf16 3-term. BK=32, dbuf, 128 KB LDS.
// LDS row: 128 B = 8 granules(16B), granule g' stores global granule g'^(row&7);
// g<4 -> hi k[g*16..), g>=4 -> lo. Staged via inverse-swizzled global source.
// MODE 0: out[b][h][s][64]. MODE 1: out[row][N].
template <int MODE, int NG>
__global__ __launch_bounds__(512, 2)
void gemm_big(GemmArgs args) {
  const int K = 1024, N = 1024;
  __shared__ __align__(16) unsigned short lA[2][256 * 64];
  __shared__ __align__(16) unsigned short lB[2][256 * 64];
  const int tid = threadIdx.x;
  const int lane = tid & 63, w = tid >> 6;

  // XCD-aware bijective swizzle (nwg % 8 == 0)
  const int nwg = NG * 64;
  const int orig = blockIdx.x;
  const int swz = (orig & 7) * (nwg >> 3) + (orig >> 3);
  const int g = swz >> 6;          // 64 blocks per gemm (16 M x 4 N)
  const int tl = swz & 63;
  const int m0 = (tl >> 2) * 256, n0 = (tl & 3) * 256;

  const unsigned short* Ahi = args.Ahi[g]; const unsigned short* Alo = args.Alo[g];
  const unsigned short* Bhi = args.Bhi[g]; const unsigned short* Blo = args.Blo[g];
  const float* bias = args.bias[g];
  float* out = args.out[g];

  const int wm = (w >> 2) * 128, wn = (w & 3) * 64;   // wave tile 128x64

  // staging source pointers: lane l writes LDS (rowblk*128B + l*16B)
  // -> row rowblk + (l>>3), stored granule l&7 must hold global granule sp.
  const int sp = (lane & 7) ^ (lane >> 3);
  const int koff = (sp & 3) * 8;
  const unsigned short* aBase = (sp < 4 ? Ahi : Alo) + koff;
  const unsigned short* bBase = (sp < 4 ? Bhi : Blo) + koff;
  const unsigned short* aP[4]; const unsigned short* bP[4];
  int ldsRow[4];
  #pragma unroll
  for (int r = 0; r < 4; ++r) {
    const int rowblk = r * 64 + w * 8;
    ldsRow[r] = rowblk * 64;   // shorts
    aP[r] = aBase + (size_t)(m0 + rowblk + (lane >> 3)) * K;
    bP[r] = bBase + (size_t)(n0 + rowblk + (lane >> 3)) * K;
  }

  f32x4 acc[8][4] = {};
  const int fr = lane & 15, gh = lane >> 4;

  // prologue: stage tile 0 into buf 0
  #pragma unroll
  for (int r = 0; r < 4; ++r) {
    gld_lds16(aP[r], &lA[0][ldsRow[r]]);
    gld_lds16(bP[r], &lB[0][ldsRow[r]]);
  }
  asm volatile("s_waitcnt vmcnt(0)" ::: "memory");
  __builtin_amdgcn_s_barrier();
  __builtin_amdgcn_sched_barrier(0);

  #pragma unroll 1
  for (int kt2 = 0; kt2 < K; kt2 += 64) {
    #pragma unroll
    for (int half = 0; half < 2; ++half) {
      const int buf = half;
      const int kt = kt2 + half * 32;
      const int nkt = kt + 32;
      const bool doStage = (nkt < K);
      s16x8 bh[4], bl[4];
      #pragma unroll
      for (int p = 0; p < 4; ++p) {
        // ds reads for this phase
        if (p == 0) {
          #pragma unroll
          for (int nt = 0; nt < 4; ++nt) {
            const int row = wn + nt * 16 + fr, x = row & 7;
            bh[nt] = *(const s16x8*)&lB[buf][row * 64 + ((gh ^ x) << 3)];
            bl[nt] = *(const s16x8*)&lB[buf][row * 64 + (((4 | gh) ^ x) << 3)];
          }
        }
        s16x8 ah[2], al[2];
        #pragma unroll
        for (int i = 0; i < 2; ++i) {
          const int row = wm + (p * 2 + i) * 16 + fr, x = row & 7;
          ah[i] = *(const s16x8*)&lA[buf][row * 64 + ((gh ^ x) << 3)];
          al[i] = *(const s16x8*)&lA[buf][row * 64 + (((4 | gh) ^ x) << 3)];
        }
        // issue next tile's staging early (phases 0-1, 4 loads each)
        if (doStage && p < 2) {
          gld_lds16(aP[p * 2 + 0] + nkt, &lA[buf ^ 1][ldsRow[p * 2 + 0]]);
          gld_lds16(aP[p * 2 + 1] + nkt, &lA[buf ^ 1][ldsRow[p * 2 + 1]]);
          gld_lds16(bP[p * 2 + 0] + nkt, &lB[buf ^ 1][ldsRow[p * 2 + 0]]);
          gld_lds16(bP[p * 2 + 1] + nkt, &lB[buf ^ 1][ldsRow[p * 2 + 1]]);
        }
        __builtin_amdgcn_s_barrier();
        asm volatile("s_waitcnt lgkmcnt(0)" ::: "memory");
        __builtin_amdgcn_sched_barrier(0);
        __builtin_amdgcn_s_setprio(1);
        #pragma unroll
        for (int i = 0; i < 2; ++i)
          #pragma unroll
          for (int nt = 0; nt < 4; ++nt) {
            acc[p * 2 + i][nt] = MFMA16(ah[i], bh[nt], acc[p * 2 + i][nt]);
            acc[p * 2 + i][nt] = MFMA16(ah[i], bl[nt], acc[p * 2 + i][nt]);
            acc[p * 2 + i][nt] = MFMA16(al[i], bh[nt], acc[p * 2 + i][nt]);
          }
        __builtin_amdgcn_s_setprio(0);
        if (p == 3) {
          asm volatile("s_waitcnt vmcnt(0)" ::: "memory");   // next tile staged
        }
        __builtin_amdgcn_s_barrier();
        __builtin_amdgcn_sched_barrier(0);
      }
    }
  }

  // epilogue: C/D layout col = lane&15, row = (lane>>4)*4 + j
  float bv[4];
  #pragma unroll
  for (int nt = 0; nt < 4; ++nt) bv[nt] = bias[n0 + wn + nt * 16 + fr];
  #pragma unroll
  for (int mt = 0; mt < 8; ++mt) {
    const int gm = m0 + wm + mt * 16 + (gh << 2);
    #pragma unroll
    for (int nt = 0; nt < 4; ++nt) {
      const int gn = n0 + wn + nt * 16 + fr;
      f32x4 r = acc[mt][nt];
      #pragma unroll
      for (int j = 0; j < 4; ++j) {
        const int row = gm + j;
        const float val = r[j] + bv[nt];
        if (MODE == 0) {
          size_t off = (((size_t)((row >> 11) * 16 + (gn >> 6))) * 2048 + (row & 2047)) * 64 + (gn & 63);
          out[off] = val;
        } else {
          out[(size_t)row * N + gn] = val;
        }
      }
    }
  }
}

// ---------- kernel 3b: 128x128 4-wave GEMM (O-proj; full CU coverage) ----------
template <int MODE, int NG>
__global__ __launch_bounds__(256, 2)
void gemm_split(GemmArgs args) {
  const int K = 1024, N = 1024;
  __shared__ __align__(16) unsigned short lA[2][128 * 64];
  __shared__ __align__(16) unsigned short lB[2][128 * 64];
  const int tid = threadIdx.x;
  const int lane = tid & 63, wid = tid >> 6;

  const int nwg = NG * 256;
  const int orig = blockIdx.x;
  const int swz = (orig & 7) * (nwg >> 3) + (orig >> 3);
  const int g = swz >> 8;
  const int tl = swz & 255;
  const int m0 = (tl >> 3) * 128, n0 = (tl & 7) * 128;

  const unsigned short* Ahi = args.Ahi[g]; const unsigned short* Alo = args.Alo[g];
  const unsigned short* Bhi = args.Bhi[g]; const unsigned short* Blo = args.Blo[g];
  const float* bias = args.bias[g];
  float* out = args.out[g];

  const int wm = (wid >> 1) * 64, wn = (wid & 1) * 64;

  const int sp = (lane & 7) ^ (lane >> 3);
  const int koff = (sp & 3) * 8;
  const unsigned short* aSrc[4]; const unsigned short* bSrc[4];
  #pragma unroll
  for (int i = 0; i < 4; ++i) {
    const int seg = wid * 4 + i;
    const int rA = m0 + seg * 8 + (lane >> 3);
    const int rB = n0 + seg * 8 + (lane >> 3);
    aSrc[i] = (sp < 4 ? Ahi : Alo) + (size_t)rA * K + koff;
    bSrc[i] = (sp < 4 ? Bhi : Blo) + (size_t)rB * K + koff;
  }

  f32x4 acc[4][4] = {};

  auto stage = [&](int buf, int kt) {
    #pragma unroll
    for (int i = 0; i < 4; ++i) {
      const int seg = wid * 4 + i;
      gld_lds16(aSrc[i] + kt, &lA[buf][seg * 512]);
      gld_lds16(bSrc[i] + kt, &lB[buf][seg * 512]);
    }
  };

  const int fr = lane & 15;
  const int gh = lane >> 4;

  auto compute = [&](int buf) {
    s16x8 ah[4], al[4], bh[4], bl[4];
    #pragma unroll
    for (int t = 0; t < 4; ++t) {
      const int ar = wm + t * 16 + fr, ax = ar & 7;
      ah[t] = *(const s16x8*)&lA[buf][ar * 64 + ((gh ^ ax) << 3)];
      al[t] = *(const s16x8*)&lA[buf][ar * 64 + (((4 | gh) ^ ax) << 3)];
      const int br = wn + t * 16 + fr, bx = br & 7;
      bh[t] = *(const s16x8*)&lB[buf][br * 64 + ((gh ^ bx) << 3)];
      bl[t] = *(const s16x8*)&lB[buf][br * 64 + (((4 | gh) ^ bx) << 3)];
    }
    #pragma unroll
    for (int mt = 0; mt < 4; ++mt)
      #pragma unroll
      for (int nt = 0; nt < 4; ++nt) {
        acc[mt][nt] = MFMA16(ah[mt], bh[nt], acc[mt][nt]);
        acc[mt][nt] = MFMA16(ah[mt], bl[nt], acc[mt][nt]);
        acc[mt][nt] = MFMA16(al[mt], bh[nt], acc[mt][nt]);
      }
  };

  stage(0, 0);
  __syncthreads();
  #pragma unroll 1
  for (int kt2 = 0; kt2 < K; kt2 += 64) {
    stage(1, kt2 + 32);
    compute(0);
    __syncthreads();
    if (kt2 + 64 < K) stage(0, kt2 + 64);
    compute(1);
    __syncthreads();
  }

  #pragma unroll
  for (int mt = 0; mt < 4; ++mt) {
    #pragma unroll
    for (int nt = 0; nt < 4; ++nt) {
      const int gm = m0 + wm + mt * 16 + ((lane >> 4) << 2);
      const int gn = n0 + wn + nt * 16 + (lane & 15);
      const float bvv = bias[gn];
      f32x4 r = acc[mt][nt];
      #pragma unroll
      for (int j = 0; j < 4; ++j) {
        int row = gm + j;
        float val = r[j] + bvv;
        if (MODE == 0) {
          size_t off = (((size_t)((row >> 11) * 16 + (gn >> 6))) * 2048 + (row & 2047)) * 64 + (gn & 63);
          out[off] = val;
        } else {
          out[(size_t)row * N + gn] = val;
        }
      }
    }
  }
}

// ---------- kernel 4: block-diagonal attention, f32 core ----------
__global__ __launch_bounds__(256, 3)
void attn_block(const float* __restrict__ Q, const float* __restrict__ Kt,
                const float* __restrict__ V,
                unsigned short* __restrict__ Xhi, unsigned short* __restrict__ Xlo) {
  __shared__ __align__(16) float qs[64 * 68];
  __shared__ __align__(16) float ks[64 * 65];
  __shared__ __align__(16) float vs[64 * 65];
  const int tid = threadIdx.x;
  const int lane = tid & 63, w = tid >> 6;
  const int hb = blockIdx.x >> 5;
  const int qb = blockIdx.x & 31;
  const size_t base = ((size_t)hb * 2048 + qb * 64) * 64;

  for (int i = 0; i < 4; ++i) {
    int idx = i * 256 + tid;
    int row = idx >> 4, c4 = (idx & 15) * 4;
    float4 qv = *(const float4*)&Q[base + (size_t)row * 64 + c4];
    float4 kv = *(const float4*)&Kt[base + (size_t)row * 64 + c4];
    float4 vv = *(const float4*)&V[base + (size_t)row * 64 + c4];
    *(float4*)&qs[row * 68 + c4] = qv;
    ks[row * 65 + c4 + 0] = kv.x; ks[row * 65 + c4 + 1] = kv.y;
    ks[row * 65 + c4 + 2] = kv.z; ks[row * 65 + c4 + 3] = kv.w;
    vs[row * 65 + c4 + 0] = vv.x; vs[row * 65 + c4 + 1] = vv.y;
    vs[row * 65 + c4 + 2] = vv.z; vs[row * 65 + c4 + 3] = vv.w;
  }
  __syncthreads();

  float sc[16];
  #pragma unroll
  for (int r = 0; r < 16; ++r) sc[r] = 0.f;
  for (int d4 = 0; d4 < 64; d4 += 4) {
    float k0 = ks[lane * 65 + d4 + 0], k1 = ks[lane * 65 + d4 + 1];
    float k2 = ks[lane * 65 + d4 + 2], k3 = ks[lane * 65 + d4 + 3];
    #pragma unroll
    for (int r = 0; r < 16; ++r) {
      const float4 qv = *(const float4*)&qs[(w * 16 + r) * 68 + d4];
      sc[r] += qv.x * k0 + qv.y * k1 + qv.z * k2 + qv.w * k3;
    }
  }
  #pragma unroll
  for (int r = 0; r < 16; ++r) {
    float s = sc[r] * 0.125f;
    float m = s;
    #pragma unroll
    for (int off = 32; off > 0; off >>= 1) m = fmaxf(m, __shfl_xor(m, off, 64));
    float p = __expf(s - m);
    float sum = p;
    #pragma unroll
    for (int off = 32; off > 0; off >>= 1) sum += __shfl_xor(sum, off, 64);
    sc[r] = p / sum;
  }
  #pragma unroll
  for (int r = 0; r < 16; ++r) qs[(w * 16 + r) * 68 + lane] = sc[r];

  float xa[16];
  #pragma unroll
  for (int r = 0; r < 16; ++r) xa[r] = 0.f;
  for (int c4 = 0; c4 < 64; c4 += 4) {
    float v0 = vs[(c4 + 0) * 65 + lane], v1 = vs[(c4 + 1) * 65 + lane];
    float v2 = vs[(c4 + 2) * 65 + lane], v3 = vs[(c4 + 3) * 65 + lane];
    #pragma unroll
    for (int r = 0; r < 16; ++r) {
      const float4 pv = *(const float4*)&qs[(w * 16 + r) * 68 + c4];
      xa[r] += pv.x * v0 + pv.y * v1 + pv.z * v2 + pv.w * v3;
    }
  }
  const int b = hb >> 4, h = hb & 15;
  #pragma unroll
  for (int r = 0; r < 16; ++r) {
    float val = xa[r];
    unsigned short hx = f2bf(val);
    unsigned short lx = f2bf(val - bf2f(hx));
    size_t off = ((size_t)(b * 2048 + qb * 64 + w * 16 + r)) * 1024 + h * 64 + lane;
    Xhi[off] = hx; Xlo[off] = lx;
  }
}

// ---------- launch ----------
extern "C" void kernel_launch(void* const* d_in, const int* in_sizes, int n_in,
                              void* d_out, int out_size, void* d_ws, size_t ws_size,
                              hipStream_t stream) {
  const float* query = (const float*)d_in[0];
  const float* key   = (const float*)d_in[1];
  const float* value = (const float*)d_in[2];
  const float* Wq = (const float*)d_in[3]; const float* bq = (const float*)d_in[4];
  const float* Wk = (const float*)d_in[5]; const float* bk = (const float*)d_in[6];
  const float* Wv = (const float*)d_in[7]; const float* bv = (const float*)d_in[8];
  const float* Wo = (const float*)d_in[9]; const float* bo = (const float*)d_in[10];
  float* out = (float*)d_out;

  const size_t W_E = 1024 * 1024;
  const size_t X_E = 4096 * 1024;
  unsigned char* p = (unsigned char*)d_ws;
  auto take = [&](size_t bytes) { void* r = (void*)p; p += bytes; return r; };

  unsigned short* wtq_hi = (unsigned short*)take(W_E * 2);
  unsigned short* wtq_lo = (unsigned short*)take(W_E * 2);
  unsigned short* wtk_hi = (unsigned short*)take(W_E * 2);
  unsigned short* wtk_lo = (unsigned short*)take(W_E * 2);
  unsigned short* wtv_hi = (unsigned short*)take(W_E * 2);
  unsigned short* wtv_lo = (unsigned short*)take(W_E * 2);
  unsigned short* wto_hi = (unsigned short*)take(W_E * 2);
  unsigned short* wto_lo = (unsigned short*)take(W_E * 2);
  unsigned short* xq_hi = (unsigned short*)take(X_E * 2);
  unsigned short* xq_lo = (unsigned short*)take(X_E * 2);
  unsigned short* xk_hi = (unsigned short*)take(X_E * 2);
  unsigned short* xk_lo = (unsigned short*)take(X_E * 2);
  unsigned short* xv_hi = (unsigned short*)take(X_E * 2);
  unsigned short* xv_lo = (unsigned short*)take(X_E * 2);
  float* Qf = (float*)take(X_E * 4);
  float* Kf = (float*)take(X_E * 4);
  float* Vf = (float*)take(X_E * 4);
  unsigned short* ao_hi = (unsigned short*)take(X_E * 2);
  unsigned short* ao_lo = (unsigned short*)take(X_E * 2);
  (void)ws_size; (void)in_sizes; (void)n_in; (void)out_size;

  transw<<<dim3(256, 4), 256, 0, stream>>>(Wq, wtq_hi, wtq_lo, Wk, wtk_hi, wtk_lo,
                                           Wv, wtv_hi, wtv_lo, Wo, wto_hi, wto_lo);
  convert_x3<<<dim3(4096, 3), 256, 0, stream>>>(query, xq_hi, xq_lo,
                                                key, xk_hi, xk_lo,
                                                value, xv_hi, xv_lo);
  // QKV: 256x256 8-wave phase-split kernel, 192 blocks
  GemmArgs qkv = {};
  qkv.Ahi[0] = xq_hi; qkv.Alo[0] = xq_lo; qkv.Bhi[0] = wtq_hi; qkv.Blo[0] = wtq_lo;
  qkv.bias[0] = bq;   qkv.out[0] = Qf;
  qkv.Ahi[1] = xk_hi; qkv.Alo[1] = xk_lo; qkv.Bhi[1] = wtk_hi; qkv.Blo[1] = wtk_lo;
  qkv.bias[1] = bk;   qkv.out[1] = Kf;
  qkv.Ahi[2] = xv_hi; qkv.Alo[2] = xv_lo; qkv.Bhi[2] = wtv_hi; qkv.Blo[2] = wtv_lo;
  qkv.bias[2] = bv;   qkv.out[2] = Vf;
  gemm_big<0, 3><<<dim3(192), 512, 0, stream>>>(qkv);
  // attention
  attn_block<<<dim3(1024), 256, 0, stream>>>(Qf, Kf, Vf, ao_hi, ao_lo);
  // O-proj: 128x128 kernel, 256 blocks (full CU coverage)
  GemmArgs og = {};
  og.Ahi[0] = ao_hi; og.Alo[0] = ao_lo; og.Bhi[0] = wto_hi; og.Blo[0] = wto_lo;
  og.bias[0] = bo;   og.out[0] = out;
  gemm_split<1, 1><<<dim3(256), 256, 0, stream>>>(og);
}

// Round 4
// 155.586 us; speedup vs baseline: 1.5043x; 1.1797x over previous
//
#include <hip/hip_runtime.h>
#include <hip/hip_bf16.h>

// ---------- helpers ----------
typedef __attribute__((ext_vector_type(4))) float f32x4;
typedef __attribute__((ext_vector_type(8))) short s16x8;

#define MFMA16(a, b, c) __builtin_amdgcn_mfma_f32_16x16x32_bf16(a, b, c, 0, 0, 0)

__device__ __forceinline__ void gld_lds16(const void* g, void* l) {
  __builtin_amdgcn_global_load_lds(
      (const __attribute__((address_space(1))) unsigned int*)g,
      (__attribute__((address_space(3))) unsigned int*)l, 16, 0, 0);
}

__device__ __forceinline__ unsigned short f2bf(float f) {
  union { __hip_bfloat16 b; unsigned short u; } cv;
  cv.b = __float2bfloat16(f);
  return cv.u;
}
__device__ __forceinline__ float bf2f(unsigned short u) {
  union { unsigned short u; __hip_bfloat16 b; } cv;
  cv.u = u;
  return __bfloat162float(cv.b);
}

// ---------- kernel 1: W [K][N] f32 -> W^T [N][K] split bf16 hi/lo ----------
// Weights keep hi+lo (B-side of the 2-term GEMM: a_hi*(b_hi + b_lo)).
__global__ void transw(const float* W0, unsigned short* H0, unsigned short* L0,
                       const float* W1, unsigned short* H1, unsigned short* L1,
                       const float* W2, unsigned short* H2, unsigned short* L2,
                       const float* W3, unsigned short* H3, unsigned short* L3) {
  __shared__ float tile[64 * 65];
  const float* W; unsigned short* H; unsigned short* L;
  switch (blockIdx.y) {
    case 0: W = W0; H = H0; L = L0; break;
    case 1: W = W1; H = H1; L = L1; break;
    case 2: W = W2; H = H2; L = L2; break;
    default: W = W3; H = H3; L = L3; break;
  }
  const int t = threadIdx.x;
  const int tk0 = (blockIdx.x & 15) * 64;   // k tile
  const int tn0 = (blockIdx.x >> 4) * 64;   // n tile
  for (int i = 0; i < 16; ++i) {
    int idx = i * 256 + t;
    int r = idx >> 6, c = idx & 63;
    tile[r * 65 + c] = W[(size_t)(tk0 + r) * 1024 + tn0 + c];
  }
  __syncthreads();
  for (int i = 0; i < 16; ++i) {
    int idx = i * 256 + t;
    int r = idx >> 6, c = idx & 63;   // r: n offset, c: k offset
    float v = tile[c * 65 + r];
    unsigned short hx = f2bf(v);
    unsigned short lx = f2bf(v - bf2f(hx));
    size_t off = (size_t)(tn0 + r) * 1024 + tk0 + c;
    H[off] = hx; L[off] = lx;
  }
}

// ---------- kernel 2: X [4096][1024] f32 -> bf16 hi only (A-side) ----------
__global__ void convert_x3(const float* A0, unsigned short* H0,
                           const float* A1, unsigned short* H1,
                           const float* A2, unsigned short* H2) {
  const float* src; unsigned short* h;
  switch (blockIdx.y) {
    case 0: src = A0; h = H0; break;
    case 1: src = A1; h = H1; break;
    default: src = A2; h = H2; break;
  }
  int i = blockIdx.x * 256 + threadIdx.x;   // float4 index
  float4 v = ((const float4*)src)[i];
  ((ushort4*)h)[i] = make_ushort4(f2bf(v.x), f2bf(v.y), f2bf(v.z), f2bf(v.w));
}

struct GemmArgs {
  const unsigned short* Ahi[3];
  const unsigned short* Bhi[3]; const unsigned short* Blo[3];
  const float* bias[3];
  float* out[3];
};

// ---------- kernel 3a: 256x256 8-wave phase-split GEMM (QKV) ----------
// C = A_hi[M,K] * (B_hi+B_lo)^T[N,K] + bias  (2-term split-bf16).
// BK=32, dbuf, 128 KB LDS. LDS row: 128 B = 8 granules(16B); granule g'
// stores global granule g'^(row&7); g<4 -> hi k[g*16..), g>=4 -> lo.
// A's lo-slots are staged with duplicate hi bytes (valid addr, never read).
// MODE 0: out[b][h][s][64]. MODE 1: out[row][N].
template <int MODE, int NG>
__global__ __launch_bounds__(512, 2)
void gemm_big(GemmArgs args) {
  const int K = 1024, N = 1024;
  __shared__ __align__(16) unsigned short lA[2][256 * 64];
  __shared__ __align__(16) unsigned short lB[2][256 * 64];
  const int tid = threadIdx.x;
  const int lane = tid & 63, w = tid >> 6;

  // XCD-aware bijective swizzle (nwg % 8 == 0)
  const int nwg = NG * 64;
  const int orig = blockIdx.x;
  const int swz = (orig & 7) * (nwg >> 3) + (orig >> 3);
  const int g = swz >> 6;          // 64 blocks per gemm (16 M x 4 N)
  const int tl = swz & 63;
  const int m0 = (tl >> 2) * 256, n0 = (tl & 3) * 256;

  const unsigned short* Ahi = args.Ahi[g];
  const unsigned short* Bhi = args.Bhi[g]; const unsigned short* Blo = args.Blo[g];
  const float* bias = args.bias[g];
  float* out = args.out[g];

  const int wm = (w >> 2) * 128, wn = (w & 3) * 64;   // wave tile 128x64

  // staging: lane l -> row rowblk+(l>>3), slot l&7 holds global granule sp.
  const int sp = (lane & 7) ^ (lane >> 3);
  const int koff = (sp & 3) * 8;
  const unsigned short* aBase = Ahi + koff;                    // lo-slots: dup hi
  const unsigned short* bBase = (sp < 4 ? Bhi : Blo) + koff;
  const unsigned short* aP[4]; const unsigned short* bP[4];
  int ldsRow[4];
  #pragma unroll
  for (int r = 0; r < 4; ++r) {
    const int rowblk = r * 64 + w * 8;
    ldsRow[r] = rowblk * 64;   // shorts
    aP[r] = aBase + (size_t)(m0 + rowblk + (lane >> 3)) * K;
    bP[r] = bBase + (size_t)(n0 + rowblk + (lane >> 3)) * K;
  }

  f32x4 acc[8][4] = {};
  const int fr = lane & 15, gh = lane >> 4;

  // prologue: stage tile 0 into buf 0
  #pragma unroll
  for (int r = 0; r < 4; ++r) {
    gld_lds16(aP[r], &lA[0][ldsRow[r]]);
    gld_lds16(bP[r], &lB[0][ldsRow[r]]);
  }
  asm volatile("s_waitcnt vmcnt(0)" ::: "memory");
  __builtin_amdgcn_s_barrier();
  __builtin_amdgcn_sched_barrier(0);

  #pragma unroll 1
  for (int kt2 = 0; kt2 < K; kt2 += 64) {
    #pragma unroll
    for (int half = 0; half < 2; ++half) {
      const int buf = half;
      const int kt = kt2 + half * 32;
      const int nkt = kt + 32;
      const bool doStage = (nkt < K);
      s16x8 bh[4], bl[4];
      #pragma unroll
      for (int p = 0; p < 4; ++p) {
        if (p == 0) {
          #pragma unroll
          for (int nt = 0; nt < 4; ++nt) {
            const int row = wn + nt * 16 + fr, x = row & 7;
            bh[nt] = *(const s16x8*)&lB[buf][row * 64 + ((gh ^ x) << 3)];
            bl[nt] = *(const s16x8*)&lB[buf][row * 64 + (((4 | gh) ^ x) << 3)];
          }
        }
        s16x8 ah[2];
        #pragma unroll
        for (int i = 0; i < 2; ++i) {
          const int row = wm + (p * 2 + i) * 16 + fr, x = row & 7;
          ah[i] = *(const s16x8*)&lA[buf][row * 64 + ((gh ^ x) << 3)];
        }
        if (doStage && p < 2) {
          gld_lds16(aP[p * 2 + 0] + nkt, &lA[buf ^ 1][ldsRow[p * 2 + 0]]);
          gld_lds16(aP[p * 2 + 1] + nkt, &lA[buf ^ 1][ldsRow[p * 2 + 1]]);
          gld_lds16(bP[p * 2 + 0] + nkt, &lB[buf ^ 1][ldsRow[p * 2 + 0]]);
          gld_lds16(bP[p * 2 + 1] + nkt, &lB[buf ^ 1][ldsRow[p * 2 + 1]]);
        }
        __builtin_amdgcn_s_barrier();
        asm volatile("s_waitcnt lgkmcnt(0)" ::: "memory");
        __builtin_amdgcn_sched_barrier(0);
        __builtin_amdgcn_s_setprio(1);
        #pragma unroll
        for (int i = 0; i < 2; ++i)
          #pragma unroll
          for (int nt = 0; nt < 4; ++nt) {
            acc[p * 2 + i][nt] = MFMA16(ah[i], bh[nt], acc[p * 2 + i][nt]);
            acc[p * 2 + i][nt] = MFMA16(ah[i], bl[nt], acc[p * 2 + i][nt]);
          }
        __builtin_amdgcn_s_setprio(0);
        if (p == 3) {
          asm volatile("s_waitcnt vmcnt(0)" ::: "memory");   // next tile staged
        }
        __builtin_amdgcn_s_barrier();
        __builtin_amdgcn_sched_barrier(0);
      }
    }
  }

  // epilogue: C/D layout col = lane&15, row = (lane>>4)*4 + j
  float bv[4];
  #pragma unroll
  for (int nt = 0; nt < 4; ++nt) bv[nt] = bias[n0 + wn + nt * 16 + fr];
  #pragma unroll
  for (int mt = 0; mt < 8; ++mt) {
    const int gm = m0 + wm + mt * 16 + (gh << 2);
    #pragma unroll
    for (int nt = 0; nt < 4; ++nt) {
      const int gn = n0 + wn + nt * 16 + fr;
      f32x4 r = acc[mt][nt];
      #pragma unroll
      for (int j = 0; j < 4; ++j) {
        const int row = gm + j;
        const float val = r[j] + bv[nt];
        if (MODE == 0) {
          size_t off = (((size_t)((row >> 11) * 16 + (gn >> 6))) * 2048 + (row & 2047)) * 64 + (gn & 63);
          out[off] = val;
        } else {
          out[(size_t)row * N + gn] = val;
        }
      }
    }
  }
}

// ---------- kernel 3b: 128x128 4-wave GEMM (O-proj; full CU coverage) ----------
template <int MODE, int NG>
__global__ __launch_bounds__(256, 2)
void gemm_split(GemmArgs args) {
  const int K = 1024, N = 1024;
  __shared__ __align__(16) unsigned short lA[2][128 * 64];
  __shared__ __align__(16) unsigned short lB[2][128 * 64];
  const int tid = threadIdx.x;
  const int lane = tid & 63, wid = tid >> 6;

  const int nwg = NG * 256;
  const int orig = blockIdx.x;
  const int swz = (orig & 7) * (nwg >> 3) + (orig >> 3);
  const int g = swz >> 8;
  const int tl = swz & 255;
  const int m0 = (tl >> 3) * 128, n0 = (tl & 7) * 128;

  const unsigned short* Ahi = args.Ahi[g];
  const unsigned short* Bhi = args.Bhi[g]; const unsigned short* Blo = args.Blo[g];
  const float* bias = args.bias[g];
  float* out = args.out[g];

  const int wm = (wid >> 1) * 64, wn = (wid & 1) * 64;

  const int sp = (lane & 7) ^ (lane >> 3);
  const int koff = (sp & 3) * 8;
  const unsigned short* aSrc[4]; const unsigned short* bSrc[4];
  #pragma unroll
  for (int i = 0; i < 4; ++i) {
    const int seg = wid * 4 + i;
    const int rA = m0 + seg * 8 + (lane >> 3);
    const int rB = n0 + seg * 8 + (lane >> 3);
    aSrc[i] = Ahi + (size_t)rA * K + koff;                  // lo-slots: dup hi
    bSrc[i] = (sp < 4 ? Bhi : Blo) + (size_t)rB * K + koff;
  }

  f32x4 acc[4][4] = {};

  auto stage = [&](int buf, int kt) {
    #pragma unroll
    for (int i = 0; i < 4; ++i) {
      const int seg = wid * 4 + i;
      gld_lds16(aSrc[i] + kt, &lA[buf][seg * 512]);
      gld_lds16(bSrc[i] + kt, &lB[buf][seg * 512]);
    }
  };

  const int fr = lane & 15;
  const int gh = lane >> 4;

  auto compute = [&](int buf) {
    s16x8 ah[4], bh[4], bl[4];
    #pragma unroll
    for (int t = 0; t < 4; ++t) {
      const int ar = wm + t * 16 + fr, ax = ar & 7;
      ah[t] = *(const s16x8*)&lA[buf][ar * 64 + ((gh ^ ax) << 3)];
      const int br = wn + t * 16 + fr, bx = br & 7;
      bh[t] = *(const s16x8*)&lB[buf][br * 64 + ((gh ^ bx) << 3)];
      bl[t] = *(const s16x8*)&lB[buf][br * 64 + (((4 | gh) ^ bx) << 3)];
    }
    #pragma unroll
    for (int mt = 0; mt < 4; ++mt)
      #pragma unroll
      for (int nt = 0; nt < 4; ++nt) {
        acc[mt][nt] = MFMA16(ah[mt], bh[nt], acc[mt][nt]);
        acc[mt][nt] = MFMA16(ah[mt], bl[nt], acc[mt][nt]);
      }
  };

  stage(0, 0);
  __syncthreads();
  #pragma unroll 1
  for (int kt2 = 0; kt2 < K; kt2 += 64) {
    stage(1, kt2 + 32);
    compute(0);
    __syncthreads();
    if (kt2 + 64 < K) stage(0, kt2 + 64);
    compute(1);
    __syncthreads();
  }

  #pragma unroll
  for (int mt = 0; mt < 4; ++mt) {
    #pragma unroll
    for (int nt = 0; nt < 4; ++nt) {
      const int gm = m0 + wm + mt * 16 + ((lane >> 4) << 2);
      const int gn = n0 + wn + nt * 16 + (lane & 15);
      const float bvv = bias[gn];
      f32x4 r = acc[mt][nt];
      #pragma unroll
      for (int j = 0; j < 4; ++j) {
        int row = gm + j;
        float val = r[j] + bvv;
        if (MODE == 0) {
          size_t off = (((size_t)((row >> 11) * 16 + (gn >> 6))) * 2048 + (row & 2047)) * 64 + (gn & 63);
          out[off] = val;
        } else {
          out[(size_t)row * N + gn] = val;
        }
      }
    }
  }
}

// ---------- kernel 4: block-diagonal attention, f32 core ----------
// Emits x as bf16 hi only (O-proj A-side).
__global__ __launch_bounds__(256, 3)
void attn_block(const float* __restrict__ Q, const float* __restrict__ Kt,
                const float* __restrict__ V, unsigned short* __restrict__ Xhi) {
  __shared__ __align__(16) float qs[64 * 68];
  __shared__ __align__(16) float ks[64 * 65];
  __shared__ __align__(16) float vs[64 * 65];
  const int tid = threadIdx.x;
  const int lane = tid & 63, w = tid >> 6;
  const int hb = blockIdx.x >> 5;
  const int qb = blockIdx.x & 31;
  const size_t base = ((size_t)hb * 2048 + qb * 64) * 64;

  for (int i = 0; i < 4; ++i) {
    int idx = i * 256 + tid;
    int row = idx >> 4, c4 = (idx & 15) * 4;
    float4 qv = *(const float4*)&Q[base + (size_t)row * 64 + c4];
    float4 kv = *(const float4*)&Kt[base + (size_t)row * 64 + c4];
    float4 vv = *(const float4*)&V[base + (size_t)row * 64 + c4];
    *(float4*)&qs[row * 68 + c4] = qv;
    ks[row * 65 + c4 + 0] = kv.x; ks[row * 65 + c4 + 1] = kv.y;
    ks[row * 65 + c4 + 2] = kv.z; ks[row * 65 + c4 + 3] = kv.w;
    vs[row * 65 + c4 + 0] = vv.x; vs[row * 65 + c4 + 1] = vv.y;
    vs[row * 65 + c4 + 2] = vv.z; vs[row * 65 + c4 + 3] = vv.w;
  }
  __syncthreads();

  float sc[16];
  #pragma unroll
  for (int r = 0; r < 16; ++r) sc[r] = 0.f;
  for (int d4 = 0; d4 < 64; d4 += 4) {
    float k0 = ks[lane * 65 + d4 + 0], k1 = ks[lane * 65 + d4 + 1];
    float k2 = ks[lane * 65 + d4 + 2], k3 = ks[lane * 65 + d4 + 3];
    #pragma unroll
    for (int r = 0; r < 16; ++r) {
      const float4 qv = *(const float4*)&qs[(w * 16 + r) * 68 + d4];
      sc[r] += qv.x * k0 + qv.y * k1 + qv.z * k2 + qv.w * k3;
    }
  }
  #pragma unroll
  for (int r = 0; r < 16; ++r) {
    float s = sc[r] * 0.125f;
    float m = s;
    #pragma unroll
    for (int off = 32; off > 0; off >>= 1) m = fmaxf(m, __shfl_xor(m, off, 64));
    float p = __expf(s - m);
    float sum = p;
    #pragma unroll
    for (int off = 32; off > 0; off >>= 1) sum += __shfl_xor(sum, off, 64);
    sc[r] = p / sum;
  }
  #pragma unroll
  for (int r = 0; r < 16; ++r) qs[(w * 16 + r) * 68 + lane] = sc[r];

  float xa[16];
  #pragma unroll
  for (int r = 0; r < 16; ++r) xa[r] = 0.f;
  for (int c4 = 0; c4 < 64; c4 += 4) {
    float v0 = vs[(c4 + 0) * 65 + lane], v1 = vs[(c4 + 1) * 65 + lane];
    float v2 = vs[(c4 + 2) * 65 + lane], v3 = vs[(c4 + 3) * 65 + lane];
    #pragma unroll
    for (int r = 0; r < 16; ++r) {
      const float4 pv = *(const float4*)&qs[(w * 16 + r) * 68 + c4];
      xa[r] += pv.x * v0 + pv.y * v1 + pv.z * v2 + pv.w * v3;
    }
  }
  const int b = hb >> 4, h = hb & 15;
  #pragma unroll
  for (int r = 0; r < 16; ++r) {
    size_t off = ((size_t)(b * 2048 + qb * 64 + w * 16 + r)) * 1024 + h * 64 + lane;
    Xhi[off] = f2bf(xa[r]);
  }
}

// ---------- launch ----------
extern "C" void kernel_launch(void* const* d_in, const int* in_sizes, int n_in,
                              void* d_out, int out_size, void* d_ws, size_t ws_size,
                              hipStream_t stream) {
  const float* query = (const float*)d_in[0];
  const float* key   = (const float*)d_in[1];
  const float* value = (const float*)d_in[2];
  const float* Wq = (const float*)d_in[3]; const float* bq = (const float*)d_in[4];
  const float* Wk = (const float*)d_in[5]; const float* bk = (const float*)d_in[6];
  const float* Wv = (const float*)d_in[7]; const float* bv = (const float*)d_in[8];
  const float* Wo = (const float*)d_in[9]; const float* bo = (const float*)d_in[10];
  float* out = (float*)d_out;

  const size_t W_E = 1024 * 1024;
  const size_t X_E = 4096 * 1024;
  unsigned char* p = (unsigned char*)d_ws;
  auto take = [&](size_t bytes) { void* r = (void*)p; p += bytes; return r; };

  unsigned short* wtq_hi = (unsigned short*)take(W_E * 2);
  unsigned short* wtq_lo = (unsigned short*)take(W_E * 2);
  unsigned short* wtk_hi = (unsigned short*)take(W_E * 2);
  unsigned short* wtk_lo = (unsigned short*)take(W_E * 2);
  unsigned short* wtv_hi = (unsigned short*)take(W_E * 2);
  unsigned short* wtv_lo = (unsigned short*)take(W_E * 2);
  unsigned short* wto_hi = (unsigned short*)take(W_E * 2);
  unsigned short* wto_lo = (unsigned short*)take(W_E * 2);
  unsigned short* xq_hi = (unsigned short*)take(X_E * 2);
  unsigned short* xk_hi = (unsigned short*)take(X_E * 2);
  unsigned short* xv_hi = (unsigned short*)take(X_E * 2);
  float* Qf = (float*)take(X_E * 4);
  float* Kf = (float*)take(X_E * 4);
  float* Vf = (float*)take(X_E * 4);
  unsigned short* ao_hi = (unsigned short*)take(X_E * 2);
  (void)ws_size; (void)in_sizes; (void)n_in; (void)out_size;

  transw<<<dim3(256, 4), 256, 0, stream>>>(Wq, wtq_hi, wtq_lo, Wk, wtk_hi, wtk_lo,
                                           Wv, wtv_hi, wtv_lo, Wo, wto_hi, wto_lo);
  convert_x3<<<dim3(4096, 3), 256, 0, stream>>>(query, xq_hi, key, xk_hi, value, xv_hi);
  // QKV: 256x256 8-wave phase-split kernel, 192 blocks
  GemmArgs qkv = {};
  qkv.Ahi[0] = xq_hi; qkv.Bhi[0] = wtq_hi; qkv.Blo[0] = wtq_lo; qkv.bias[0] = bq; qkv.out[0] = Qf;
  qkv.Ahi[1] = xk_hi; qkv.Bhi[1] = wtk_hi; qkv.Blo[1] = wtk_lo; qkv.bias[1] = bk; qkv.out[1] = Kf;
  qkv.Ahi[2] = xv_hi; qkv.Bhi[2] = wtv_hi; qkv.Blo[2] = wtv_lo; qkv.bias[2] = bv; qkv.out[2] = Vf;
  gemm_big<0, 3><<<dim3(192), 512, 0, stream>>>(qkv);
  // attention
  attn_block<<<dim3(1024), 256, 0, stream>>>(Qf, Kf, Vf, ao_hi);
  // O-proj: 128x128 kernel, 256 blocks (full CU coverage)
  GemmArgs og = {};
  og.Ahi[0] = ao_hi; og.Bhi[0] = wto_hi; og.Blo[0] = wto_lo; og.bias[0] = bo; og.out[0] = out;
  gemm_split<1, 1><<<dim3(256), 256, 0, stream>>>(og);
}

// Round 5
// 110.916 us; speedup vs baseline: 2.1102x; 1.4027x over previous
//
#include <hip/hip_runtime.h>
#include <hip/hip_bf16.h>

// ---------- helpers ----------
typedef __attribute__((ext_vector_type(4))) float f32x4;
typedef __attribute__((ext_vector_type(8))) short s16x8;

#define MFMA16(a, b, c) __builtin_amdgcn_mfma_f32_16x16x32_bf16(a, b, c, 0, 0, 0)

__device__ __forceinline__ void gld_lds16(const void* g, void* l) {
  __builtin_amdgcn_global_load_lds(
      (const __attribute__((address_space(1))) unsigned int*)g,
      (__attribute__((address_space(3))) unsigned int*)l, 16, 0, 0);
}

__device__ __forceinline__ unsigned short f2bf(float f) {
  union { __hip_bfloat16 b; unsigned short u; } cv;
  cv.b = __float2bfloat16(f);
  return cv.u;
}
__device__ __forceinline__ float bf2f(unsigned short u) {
  union { unsigned short u; __hip_bfloat16 b; } cv;
  cv.u = u;
  return __bfloat162float(cv.b);
}

// ---------- kernel 1: W [K][N] f32 -> W^T [N][K] bf16 ----------
__global__ void transw(const float* W0, unsigned short* H0,
                       const float* W1, unsigned short* H1,
                       const float* W2, unsigned short* H2,
                       const float* W3, unsigned short* H3) {
  __shared__ float tile[64 * 65];
  const float* W; unsigned short* H;
  switch (blockIdx.y) {
    case 0: W = W0; H = H0; break;
    case 1: W = W1; H = H1; break;
    case 2: W = W2; H = H2; break;
    default: W = W3; H = H3; break;
  }
  const int t = threadIdx.x;
  const int tk0 = (blockIdx.x & 15) * 64;   // k tile
  const int tn0 = (blockIdx.x >> 4) * 64;   // n tile
  for (int i = 0; i < 16; ++i) {
    int idx = i * 256 + t;
    int r = idx >> 6, c = idx & 63;
    tile[r * 65 + c] = W[(size_t)(tk0 + r) * 1024 + tn0 + c];
  }
  __syncthreads();
  for (int i = 0; i < 16; ++i) {
    int idx = i * 256 + t;
    int r = idx >> 6, c = idx & 63;   // r: n offset, c: k offset
    H[(size_t)(tn0 + r) * 1024 + tk0 + c] = f2bf(tile[c * 65 + r]);
  }
}

// ---------- kernel 2: X [4096][1024] f32 -> bf16 ----------
__global__ void convert_x3(const float* A0, unsigned short* H0,
                           const float* A1, unsigned short* H1,
                           const float* A2, unsigned short* H2) {
  const float* src; unsigned short* h;
  switch (blockIdx.y) {
    case 0: src = A0; h = H0; break;
    case 1: src = A1; h = H1; break;
    default: src = A2; h = H2; break;
  }
  int i = blockIdx.x * 256 + threadIdx.x;   // float4 index
  float4 v = ((const float4*)src)[i];
  ((ushort4*)h)[i] = make_ushort4(f2bf(v.x), f2bf(v.y), f2bf(v.z), f2bf(v.w));
}

// ---------- LDS pair-packed layout (both GEMMs) ----------
// Buffer per matrix per BK=32 half: rows are packed 2-per-LDS-row (128 B):
// lds-row r' holds matrix rows {2r',2r'+1}; logical granule s = h*4 + kslot
// (h = row parity, kslot = 8-short k group) stored at slot s' = s ^ (r'&7).
// Read (row ar, k-slot gh): idx = (ar>>1)*64 + (((ar&1)*4+gh)^((ar>>1)&7))*8.
// -> each 16-lane group hits each 4-bank group with exactly 2 lanes (free).
// Staging thread writes granule G linearly: r'=G>>3, s'=G&7, s=s'^(r'&7):
// source row = 2r' + (s>>2), k offset = (s&3)*8.

// ---------- kernel 3a: QKV bf16 GEMM, 256x256 tile, 8 waves, depth-4 ----------
struct QkvArgs {
  const unsigned short* A[3];
  const unsigned short* B[3];
  const float* bias[3];
  unsigned short* out[3];   // [b*16+h][s][64] bf16
};

__global__ __launch_bounds__(512, 2)
void gemm_qkv(QkvArgs args) {
  const int K = 1024;
  __shared__ __align__(16) unsigned short lds[4][2][8192];   // 128 KB
  const int tid = threadIdx.x;
  const int lane = tid & 63, w = tid >> 6;

  // XCD-aware bijective swizzle (192 % 8 == 0)
  const int nwg = 192;
  const int orig = blockIdx.x;
  const int swz = (orig & 7) * (nwg >> 3) + (orig >> 3);
  const int g = swz >> 6;          // 64 blocks per gemm (16 M x 4 N)
  const int tl = swz & 63;
  const int m0 = (tl >> 2) * 256, n0 = (tl & 3) * 256;

  const unsigned short* A = args.A[g];
  const unsigned short* B = args.B[g];
  const float* bias = args.bias[g];
  unsigned short* out = args.out[g];

  const int wm = (w >> 2) * 128, wn = (w & 3) * 64;   // wave tile 128x64
  const int fr = lane & 15, gh = lane >> 4;

  // staging sources: 2 granules per thread per matrix per half
  size_t aoff[2], boff[2]; int dst[2];
  #pragma unroll
  for (int i = 0; i < 2; ++i) {
    const int G = i * 512 + tid;
    const int rp = G >> 3, spr = G & 7;
    const int s = spr ^ (rp & 7);
    const int srow = 2 * rp + (s >> 2), ko = (s & 3) * 8;
    aoff[i] = (size_t)(m0 + srow) * K + ko;
    boff[i] = (size_t)(n0 + srow) * K + ko;
    dst[i] = G * 8;
  }

  auto stage = [&](int buf, int kt) {
    #pragma unroll
    for (int i = 0; i < 2; ++i) {
      gld_lds16(A + aoff[i] + kt, &lds[buf][0][dst[i]]);
      gld_lds16(B + boff[i] + kt, &lds[buf][1][dst[i]]);
    }
  };

  f32x4 acc[8][4] = {};
  const int laneoff = (fr >> 1) * 64 + ((((fr & 1) << 2) | gh) ^ (fr >> 1)) * 8;

  // prologue: stage halves 0..3
  stage(0, 0); stage(1, 32); stage(2, 64); stage(3, 96);

  #pragma unroll 1
  for (int t = 0; t < 32; ++t) {
    if (t < 29)      { asm volatile("s_waitcnt vmcnt(12)" ::: "memory"); }
    else if (t == 29){ asm volatile("s_waitcnt vmcnt(8)"  ::: "memory"); }
    else if (t == 30){ asm volatile("s_waitcnt vmcnt(4)"  ::: "memory"); }
    else             { asm volatile("s_waitcnt vmcnt(0)"  ::: "memory"); }
    __builtin_amdgcn_s_barrier();

    const int buf = t & 3;
    const unsigned short* La = &lds[buf][0][wm * 32 + laneoff];
    const unsigned short* Lb = &lds[buf][1][wn * 32 + laneoff];
    s16x8 b[4], a[8];
    #pragma unroll
    for (int nt = 0; nt < 4; ++nt) b[nt] = *(const s16x8*)&Lb[nt * 512];
    #pragma unroll
    for (int mt = 0; mt < 8; ++mt) a[mt] = *(const s16x8*)&La[mt * 512];
    #pragma unroll
    for (int mt = 0; mt < 8; ++mt)
      #pragma unroll
      for (int nt = 0; nt < 4; ++nt)
        acc[mt][nt] = MFMA16(a[mt], b[nt], acc[mt][nt]);

    __builtin_amdgcn_sched_barrier(0);
    __builtin_amdgcn_s_barrier();
    if (t + 4 < 32) stage(buf, (t + 4) * 32);
  }

  // epilogue: C/D layout col = lane&15, row = (lane>>4)*4 + j
  float bv[4];
  #pragma unroll
  for (int nt = 0; nt < 4; ++nt) bv[nt] = bias[n0 + wn + nt * 16 + fr];
  #pragma unroll
  for (int mt = 0; mt < 8; ++mt) {
    const int gm = m0 + wm + mt * 16 + (gh << 2);
    #pragma unroll
    for (int nt = 0; nt < 4; ++nt) {
      const int gn = n0 + wn + nt * 16 + fr;
      f32x4 r = acc[mt][nt];
      #pragma unroll
      for (int j = 0; j < 4; ++j) {
        const int row = gm + j;
        // [b*16+h][s][d]
        size_t off = (((size_t)((row >> 11) * 16 + (gn >> 6))) * 2048 + (row & 2047)) * 64 + (gn & 63);
        out[off] = f2bf(r[j] + bv[nt]);
      }
    }
  }
}

// ---------- kernel 3b: O-proj bf16 GEMM, 128x128 tile, 4 waves, depth-3 ----------
__global__ __launch_bounds__(256, 3)
void gemm_oproj(const unsigned short* __restrict__ A, const unsigned short* __restrict__ B,
                const float* __restrict__ bias, float* __restrict__ out) {
  const int K = 1024, N = 1024;
  __shared__ __align__(16) unsigned short lds[3][2][4096];   // 48 KB
  const int tid = threadIdx.x;
  const int lane = tid & 63, wid = tid >> 6;

  const int nwg = 256;
  const int orig = blockIdx.x;
  const int swz = (orig & 7) * (nwg >> 3) + (orig >> 3);
  const int m0 = (swz >> 3) * 128, n0 = (swz & 7) * 128;

  const int wm = (wid >> 1) * 64, wn = (wid & 1) * 64;
  const int fr = lane & 15, gh = lane >> 4;

  size_t aoff[2], boff[2]; int dst[2];
  #pragma unroll
  for (int i = 0; i < 2; ++i) {
    const int G = i * 256 + tid;
    const int rp = G >> 3, spr = G & 7;
    const int s = spr ^ (rp & 7);
    const int srow = 2 * rp + (s >> 2), ko = (s & 3) * 8;
    aoff[i] = (size_t)(m0 + srow) * K + ko;
    boff[i] = (size_t)(n0 + srow) * K + ko;
    dst[i] = G * 8;
  }

  auto stage = [&](int buf, int kt) {
    #pragma unroll
    for (int i = 0; i < 2; ++i) {
      gld_lds16(A + aoff[i] + kt, &lds[buf][0][dst[i]]);
      gld_lds16(B + boff[i] + kt, &lds[buf][1][dst[i]]);
    }
  };

  f32x4 acc[4][4] = {};
  const int laneoff = (fr >> 1) * 64 + ((((fr & 1) << 2) | gh) ^ (fr >> 1)) * 8;

  stage(0, 0); stage(1, 32); stage(2, 64);

  #pragma unroll 1
  for (int t = 0; t < 32; ++t) {
    if (t < 30)      { asm volatile("s_waitcnt vmcnt(8)" ::: "memory"); }
    else if (t == 30){ asm volatile("s_waitcnt vmcnt(4)" ::: "memory"); }
    else             { asm volatile("s_waitcnt vmcnt(0)" ::: "memory"); }
    __builtin_amdgcn_s_barrier();

    const int buf = t % 3;
    const unsigned short* La = &lds[buf][0][wm * 32 + laneoff];
    const unsigned short* Lb = &lds[buf][1][wn * 32 + laneoff];
    s16x8 b[4], a[4];
    #pragma unroll
    for (int nt = 0; nt < 4; ++nt) b[nt] = *(const s16x8*)&Lb[nt * 512];
    #pragma unroll
    for (int mt = 0; mt < 4; ++mt) a[mt] = *(const s16x8*)&La[mt * 512];
    #pragma unroll
    for (int mt = 0; mt < 4; ++mt)
      #pragma unroll
      for (int nt = 0; nt < 4; ++nt)
        acc[mt][nt] = MFMA16(a[mt], b[nt], acc[mt][nt]);

    __builtin_amdgcn_sched_barrier(0);
    __builtin_amdgcn_s_barrier();
    if (t + 3 < 32) stage(buf, (t + 3) * 32);
  }

  #pragma unroll
  for (int mt = 0; mt < 4; ++mt) {
    const int gm = m0 + wm + mt * 16 + (gh << 2);
    #pragma unroll
    for (int nt = 0; nt < 4; ++nt) {
      const int gn = n0 + wn + nt * 16 + fr;
      const float bvv = bias[gn];
      f32x4 r = acc[mt][nt];
      #pragma unroll
      for (int j = 0; j < 4; ++j)
        out[(size_t)(gm + j) * N + gn] = r[j] + bvv;
    }
  }
}

// ---------- kernel 4: block-diagonal attention, f32 core, bf16 I/O ----------
__global__ __launch_bounds__(256, 3)
void attn_block(const unsigned short* __restrict__ Q, const unsigned short* __restrict__ Kt,
                const unsigned short* __restrict__ V, unsigned short* __restrict__ Xhi) {
  __shared__ __align__(16) float qs[64 * 68];   // q rows; reused for P
  __shared__ __align__(16) float ks[64 * 66];
  __shared__ __align__(16) float vs[64 * 66];
  const int tid = threadIdx.x;
  const int lane = tid & 63, w = tid >> 6;
  const int hb = blockIdx.x >> 5;
  const int qb = blockIdx.x & 31;
  const size_t base = ((size_t)hb * 2048 + qb * 64) * 64;

  for (int it = 0; it < 2; ++it) {
    int idx = it * 256 + tid;            // 8-short unit, 512 total
    int row = idx >> 3, c8 = (idx & 7) * 8;
    s16x8 qv = *(const s16x8*)&Q[base + (size_t)row * 64 + c8];
    s16x8 kv = *(const s16x8*)&Kt[base + (size_t)row * 64 + c8];
    s16x8 vv = *(const s16x8*)&V[base + (size_t)row * 64 + c8];
    *(float4*)&qs[row * 68 + c8] = make_float4(
        bf2f((unsigned short)qv[0]), bf2f((unsigned short)qv[1]),
        bf2f((unsigned short)qv[2]), bf2f((unsigned short)qv[3]));
    *(float4*)&qs[row * 68 + c8 + 4] = make_float4(
        bf2f((unsigned short)qv[4]), bf2f((unsigned short)qv[5]),
        bf2f((unsigned short)qv[6]), bf2f((unsigned short)qv[7]));
    #pragma unroll
    for (int j = 0; j < 4; ++j) {
      *(float2*)&ks[row * 66 + c8 + j * 2] = make_float2(
          bf2f((unsigned short)kv[j * 2]), bf2f((unsigned short)kv[j * 2 + 1]));
      *(float2*)&vs[row * 66 + c8 + j * 2] = make_float2(
          bf2f((unsigned short)vv[j * 2]), bf2f((unsigned short)vv[j * 2 + 1]));
    }
  }
  __syncthreads();

  // scores: lane = key index; wave owns q rows [w*16, w*16+16)
  float sc[16];
  #pragma unroll
  for (int r = 0; r < 16; ++r) sc[r] = 0.f;
  for (int d4 = 0; d4 < 64; d4 += 4) {
    float k0 = ks[lane * 66 + d4 + 0], k1 = ks[lane * 66 + d4 + 1];
    float k2 = ks[lane * 66 + d4 + 2], k3 = ks[lane * 66 + d4 + 3];
    #pragma unroll
    for (int r = 0; r < 16; ++r) {
      const float4 qv = *(const float4*)&qs[(w * 16 + r) * 68 + d4];
      sc[r] += qv.x * k0 + qv.y * k1 + qv.z * k2 + qv.w * k3;
    }
  }
  #pragma unroll
  for (int r = 0; r < 16; ++r) {
    float s = sc[r] * 0.125f;
    float m = s;
    #pragma unroll
    for (int off = 32; off > 0; off >>= 1) m = fmaxf(m, __shfl_xor(m, off, 64));
    float p = __expf(s - m);
    float sum = p;
    #pragma unroll
    for (int off = 32; off > 0; off >>= 1) sum += __shfl_xor(sum, off, 64);
    sc[r] = p / sum;
  }
  #pragma unroll
  for (int r = 0; r < 16; ++r) qs[(w * 16 + r) * 68 + lane] = sc[r];

  // PV: lane = output dim d
  float xa[16];
  #pragma unroll
  for (int r = 0; r < 16; ++r) xa[r] = 0.f;
  for (int c4 = 0; c4 < 64; c4 += 4) {
    float v0 = vs[(c4 + 0) * 66 + lane], v1 = vs[(c4 + 1) * 66 + lane];
    float v2 = vs[(c4 + 2) * 66 + lane], v3 = vs[(c4 + 3) * 66 + lane];
    #pragma unroll
    for (int r = 0; r < 16; ++r) {
      const float4 pv = *(const float4*)&qs[(w * 16 + r) * 68 + c4];
      xa[r] += pv.x * v0 + pv.y * v1 + pv.z * v2 + pv.w * v3;
    }
  }
  const int b = hb >> 4, h = hb & 15;
  #pragma unroll
  for (int r = 0; r < 16; ++r) {
    size_t off = ((size_t)(b * 2048 + qb * 64 + w * 16 + r)) * 1024 + h * 64 + lane;
    Xhi[off] = f2bf(xa[r]);
  }
}

// ---------- launch ----------
extern "C" void kernel_launch(void* const* d_in, const int* in_sizes, int n_in,
                              void* d_out, int out_size, void* d_ws, size_t ws_size,
                              hipStream_t stream) {
  const float* query = (const float*)d_in[0];
  const float* key   = (const float*)d_in[1];
  const float* value = (const float*)d_in[2];
  const float* Wq = (const float*)d_in[3]; const float* bq = (const float*)d_in[4];
  const float* Wk = (const float*)d_in[5]; const float* bk = (const float*)d_in[6];
  const float* Wv = (const float*)d_in[7]; const float* bv = (const float*)d_in[8];
  const float* Wo = (const float*)d_in[9]; const float* bo = (const float*)d_in[10];
  float* out = (float*)d_out;

  const size_t W_E = 1024 * 1024;
  const size_t X_E = 4096 * 1024;
  unsigned char* p = (unsigned char*)d_ws;
  auto take = [&](size_t bytes) { void* r = (void*)p; p += bytes; return r; };

  unsigned short* wtq = (unsigned short*)take(W_E * 2);
  unsigned short* wtk = (unsigned short*)take(W_E * 2);
  unsigned short* wtv = (unsigned short*)take(W_E * 2);
  unsigned short* wto = (unsigned short*)take(W_E * 2);
  unsigned short* xq = (unsigned short*)take(X_E * 2);
  unsigned short* xk = (unsigned short*)take(X_E * 2);
  unsigned short* xv = (unsigned short*)take(X_E * 2);
  unsigned short* Qb = (unsigned short*)take(X_E * 2);
  unsigned short* Kb = (unsigned short*)take(X_E * 2);
  unsigned short* Vb = (unsigned short*)take(X_E * 2);
  unsigned short* ao = (unsigned short*)take(X_E * 2);
  (void)ws_size; (void)in_sizes; (void)n_in; (void)out_size;

  transw<<<dim3(256, 4), 256, 0, stream>>>(Wq, wtq, Wk, wtk, Wv, wtv, Wo, wto);
  convert_x3<<<dim3(4096, 3), 256, 0, stream>>>(query, xq, key, xk, value, xv);

  QkvArgs qkv = {};
  qkv.A[0] = xq; qkv.B[0] = wtq; qkv.bias[0] = bq; qkv.out[0] = Qb;
  qkv.A[1] = xk; qkv.B[1] = wtk; qkv.bias[1] = bk; qkv.out[1] = Kb;
  qkv.A[2] = xv; qkv.B[2] = wtv; qkv.bias[2] = bv; qkv.out[2] = Vb;
  gemm_qkv<<<dim3(192), 512, 0, stream>>>(qkv);

  attn_block<<<dim3(1024), 256, 0, stream>>>(Qb, Kb, Vb, ao);

  gemm_oproj<<<dim3(256), 256, 0, stream>>>(ao, wto, bo, out);
}

// Round 6
// 86.718 us; speedup vs baseline: 2.6990x; 1.2790x over previous
//
#include <hip/hip_runtime.h>
#include <hip/hip_bf16.h>

// ---------- helpers ----------
typedef __attribute__((ext_vector_type(4))) float f32x4;
typedef __attribute__((ext_vector_type(8))) short s16x8;

#define MFMA16(a, b, c) __builtin_amdgcn_mfma_f32_16x16x32_bf16(a, b, c, 0, 0, 0)

__device__ __forceinline__ void gld_lds16(const void* g, void* l) {
  __builtin_amdgcn_global_load_lds(
      (const __attribute__((address_space(1))) unsigned int*)g,
      (__attribute__((address_space(3))) unsigned int*)l, 16, 0, 0);
}

__device__ __forceinline__ unsigned short f2bf(float f) {
  union { __hip_bfloat16 b; unsigned short u; } cv;
  cv.b = __float2bfloat16(f);
  return cv.u;
}
__device__ __forceinline__ float bf2f(unsigned short u) {
  union { unsigned short u; __hip_bfloat16 b; } cv;
  cv.u = u;
  return __bfloat162float(cv.b);
}

// ---------- kernel 1: W [K][N] f32 -> W^T [N][K] bf16 ----------
__global__ void transw(const float* W0, unsigned short* H0,
                       const float* W1, unsigned short* H1,
                       const float* W2, unsigned short* H2,
                       const float* W3, unsigned short* H3) {
  __shared__ float tile[64 * 65];
  const float* W; unsigned short* H;
  switch (blockIdx.y) {
    case 0: W = W0; H = H0; break;
    case 1: W = W1; H = H1; break;
    case 2: W = W2; H = H2; break;
    default: W = W3; H = H3; break;
  }
  const int t = threadIdx.x;
  const int tk0 = (blockIdx.x & 15) * 64;   // k tile
  const int tn0 = (blockIdx.x >> 4) * 64;   // n tile
  for (int i = 0; i < 16; ++i) {
    int idx = i * 256 + t;
    int r = idx >> 6, c = idx & 63;
    tile[r * 65 + c] = W[(size_t)(tk0 + r) * 1024 + tn0 + c];
  }
  __syncthreads();
  for (int i = 0; i < 16; ++i) {
    int idx = i * 256 + t;
    int r = idx >> 6, c = idx & 63;   // r: n offset, c: k offset
    H[(size_t)(tn0 + r) * 1024 + tk0 + c] = f2bf(tile[c * 65 + r]);
  }
}

// ---------- kernel 2: X [4096][1024] f32 -> bf16 ----------
__global__ void convert_x3(const float* A0, unsigned short* H0,
                           const float* A1, unsigned short* H1,
                           const float* A2, unsigned short* H2) {
  const float* src; unsigned short* h;
  switch (blockIdx.y) {
    case 0: src = A0; h = H0; break;
    case 1: src = A1; h = H1; break;
    default: src = A2; h = H2; break;
  }
  int i = blockIdx.x * 256 + threadIdx.x;   // float4 index
  float4 v = ((const float4*)src)[i];
  ((ushort4*)h)[i] = make_ushort4(f2bf(v.x), f2bf(v.y), f2bf(v.z), f2bf(v.w));
}

// ---------- kernel 3a: QKV bf16 GEMM, 256x256 tile, 8 waves, depth-4 ----------
// g==0,1 (Q,K): out [b*16+h][s][64]. g==2 (V): out TRANSPOSED [b*16+h][d][2048 s].
struct QkvArgs {
  const unsigned short* A[3];
  const unsigned short* B[3];
  const float* bias[3];
  unsigned short* out[3];
};

__global__ __launch_bounds__(512, 2)
void gemm_qkv(QkvArgs args) {
  const int K = 1024;
  __shared__ __align__(16) unsigned short lds[4][2][8192];   // 128 KB
  const int tid = threadIdx.x;
  const int lane = tid & 63, w = tid >> 6;

  // XCD-aware bijective swizzle (192 % 8 == 0)
  const int nwg = 192;
  const int orig = blockIdx.x;
  const int swz = (orig & 7) * (nwg >> 3) + (orig >> 3);
  const int g = swz >> 6;          // 64 blocks per gemm (16 M x 4 N)
  const int tl = swz & 63;
  const int m0 = (tl >> 2) * 256, n0 = (tl & 3) * 256;

  const unsigned short* A = args.A[g];
  const unsigned short* B = args.B[g];
  const float* bias = args.bias[g];
  unsigned short* out = args.out[g];

  const int wm = (w >> 2) * 128, wn = (w & 3) * 64;   // wave tile 128x64
  const int fr = lane & 15, gh = lane >> 4;

  // staging sources: 2 granules per thread per matrix per half
  size_t aoff[2], boff[2]; int dst[2];
  #pragma unroll
  for (int i = 0; i < 2; ++i) {
    const int G = i * 512 + tid;
    const int rp = G >> 3, spr = G & 7;
    const int s = spr ^ (rp & 7);
    const int srow = 2 * rp + (s >> 2), ko = (s & 3) * 8;
    aoff[i] = (size_t)(m0 + srow) * K + ko;
    boff[i] = (size_t)(n0 + srow) * K + ko;
    dst[i] = G * 8;
  }

  auto stage = [&](int buf, int kt) {
    #pragma unroll
    for (int i = 0; i < 2; ++i) {
      gld_lds16(A + aoff[i] + kt, &lds[buf][0][dst[i]]);
      gld_lds16(B + boff[i] + kt, &lds[buf][1][dst[i]]);
    }
  };

  f32x4 acc[8][4] = {};
  const int laneoff = (fr >> 1) * 64 + ((((fr & 1) << 2) | gh) ^ (fr >> 1)) * 8;

  // prologue: stage halves 0..3
  stage(0, 0); stage(1, 32); stage(2, 64); stage(3, 96);

  #pragma unroll 1
  for (int t = 0; t < 32; ++t) {
    if (t < 29)      { asm volatile("s_waitcnt vmcnt(12)" ::: "memory"); }
    else if (t == 29){ asm volatile("s_waitcnt vmcnt(8)"  ::: "memory"); }
    else if (t == 30){ asm volatile("s_waitcnt vmcnt(4)"  ::: "memory"); }
    else             { asm volatile("s_waitcnt vmcnt(0)"  ::: "memory"); }
    __builtin_amdgcn_s_barrier();

    const int buf = t & 3;
    const unsigned short* La = &lds[buf][0][wm * 32 + laneoff];
    const unsigned short* Lb = &lds[buf][1][wn * 32 + laneoff];
    s16x8 b[4], a[8];
    #pragma unroll
    for (int nt = 0; nt < 4; ++nt) b[nt] = *(const s16x8*)&Lb[nt * 512];
    #pragma unroll
    for (int mt = 0; mt < 8; ++mt) a[mt] = *(const s16x8*)&La[mt * 512];
    #pragma unroll
    for (int mt = 0; mt < 8; ++mt)
      #pragma unroll
      for (int nt = 0; nt < 4; ++nt)
        acc[mt][nt] = MFMA16(a[mt], b[nt], acc[mt][nt]);

    __builtin_amdgcn_sched_barrier(0);
    __builtin_amdgcn_s_barrier();
    if (t + 4 < 32) stage(buf, (t + 4) * 32);
  }

  // epilogue: C/D layout col = lane&15, row = (lane>>4)*4 + j
  float bv[4];
  #pragma unroll
  for (int nt = 0; nt < 4; ++nt) bv[nt] = bias[n0 + wn + nt * 16 + fr];
  if (g == 2) {
    // V transposed: [b*16+h][d][2048 s]; 4 consecutive s rows pack to ushort4
    #pragma unroll
    for (int mt = 0; mt < 8; ++mt) {
      const int gm = m0 + wm + mt * 16 + (gh << 2);   // s base (mult of 4)
      const int b = gm >> 11, s = gm & 2047;
      #pragma unroll
      for (int nt = 0; nt < 4; ++nt) {
        const int gn = n0 + wn + nt * 16 + fr;
        const int h = gn >> 6, d = gn & 63;
        f32x4 r = acc[mt][nt];
        ushort4 w4 = make_ushort4(f2bf(r[0] + bv[nt]), f2bf(r[1] + bv[nt]),
                                  f2bf(r[2] + bv[nt]), f2bf(r[3] + bv[nt]));
        *(ushort4*)&out[((size_t)((b * 16 + h) * 64 + d)) * 2048 + s] = w4;
      }
    }
  } else {
    #pragma unroll
    for (int mt = 0; mt < 8; ++mt) {
      const int gm = m0 + wm + mt * 16 + (gh << 2);
      #pragma unroll
      for (int nt = 0; nt < 4; ++nt) {
        const int gn = n0 + wn + nt * 16 + fr;
        f32x4 r = acc[mt][nt];
        #pragma unroll
        for (int j = 0; j < 4; ++j) {
          const int row = gm + j;
          size_t off = (((size_t)((row >> 11) * 16 + (gn >> 6))) * 2048 + (row & 2047)) * 64 + (gn & 63);
          out[off] = f2bf(r[j] + bv[nt]);
        }
      }
    }
  }
}

// ---------- kernel 3b: O-proj bf16 GEMM, 128x128 tile, 4 waves, depth-3 ----------
__global__ __launch_bounds__(256, 3)
void gemm_oproj(const unsigned short* __restrict__ A, const unsigned short* __restrict__ B,
                const float* __restrict__ bias, float* __restrict__ out) {
  const int K = 1024, N = 1024;
  __shared__ __align__(16) unsigned short lds[3][2][4096];   // 48 KB
  const int tid = threadIdx.x;
  const int lane = tid & 63, wid = tid >> 6;

  const int nwg = 256;
  const int orig = blockIdx.x;
  const int swz = (orig & 7) * (nwg >> 3) + (orig >> 3);
  const int m0 = (swz >> 3) * 128, n0 = (swz & 7) * 128;

  const int wm = (wid >> 1) * 64, wn = (wid & 1) * 64;
  const int fr = lane & 15, gh = lane >> 4;

  size_t aoff[2], boff[2]; int dst[2];
  #pragma unroll
  for (int i = 0; i < 2; ++i) {
    const int G = i * 256 + tid;
    const int rp = G >> 3, spr = G & 7;
    const int s = spr ^ (rp & 7);
    const int srow = 2 * rp + (s >> 2), ko = (s & 3) * 8;
    aoff[i] = (size_t)(m0 + srow) * K + ko;
    boff[i] = (size_t)(n0 + srow) * K + ko;
    dst[i] = G * 8;
  }

  auto stage = [&](int buf, int kt) {
    #pragma unroll
    for (int i = 0; i < 2; ++i) {
      gld_lds16(A + aoff[i] + kt, &lds[buf][0][dst[i]]);
      gld_lds16(B + boff[i] + kt, &lds[buf][1][dst[i]]);
    }
  };

  f32x4 acc[4][4] = {};
  const int laneoff = (fr >> 1) * 64 + ((((fr & 1) << 2) | gh) ^ (fr >> 1)) * 8;

  stage(0, 0); stage(1, 32); stage(2, 64);

  #pragma unroll 1
  for (int t = 0; t < 32; ++t) {
    if (t < 30)      { asm volatile("s_waitcnt vmcnt(8)" ::: "memory"); }
    else if (t == 30){ asm volatile("s_waitcnt vmcnt(4)" ::: "memory"); }
    else             { asm volatile("s_waitcnt vmcnt(0)" ::: "memory"); }
    __builtin_amdgcn_s_barrier();

    const int buf = t % 3;
    const unsigned short* La = &lds[buf][0][wm * 32 + laneoff];
    const unsigned short* Lb = &lds[buf][1][wn * 32 + laneoff];
    s16x8 b[4], a[4];
    #pragma unroll
    for (int nt = 0; nt < 4; ++nt) b[nt] = *(const s16x8*)&Lb[nt * 512];
    #pragma unroll
    for (int mt = 0; mt < 4; ++mt) a[mt] = *(const s16x8*)&La[mt * 512];
    #pragma unroll
    for (int mt = 0; mt < 4; ++mt)
      #pragma unroll
      for (int nt = 0; nt < 4; ++nt)
        acc[mt][nt] = MFMA16(a[mt], b[nt], acc[mt][nt]);

    __builtin_amdgcn_sched_barrier(0);
    __builtin_amdgcn_s_barrier();
    if (t + 3 < 32) stage(buf, (t + 3) * 32);
  }

  #pragma unroll
  for (int mt = 0; mt < 4; ++mt) {
    const int gm = m0 + wm + mt * 16 + (gh << 2);
    #pragma unroll
    for (int nt = 0; nt < 4; ++nt) {
      const int gn = n0 + wn + nt * 16 + fr;
      const float bvv = bias[gn];
      f32x4 r = acc[mt][nt];
      #pragma unroll
      for (int j = 0; j < 4; ++j)
        out[(size_t)(gm + j) * N + gn] = r[j] + bvv;
    }
  }
}

// ---------- kernel 4: block-diagonal attention, MFMA core ----------
// grid 1024 = hb*32 + qb. Q,K: [hb][2048 s][64 d] bf16. Vt: [hb][64 d][2048 s] bf16.
// LDS tiles [64][64] bf16 with granule-XOR: granule g of row r stored at slot g^(r&7).
__global__ __launch_bounds__(256, 2)
void attn_mfma(const unsigned short* __restrict__ Q, const unsigned short* __restrict__ Kb,
               const unsigned short* __restrict__ Vt, unsigned short* __restrict__ X) {
  __shared__ __align__(16) unsigned short qs[4096];
  __shared__ __align__(16) unsigned short ks2[4096];
  __shared__ __align__(16) unsigned short vs[4096];
  __shared__ __align__(16) unsigned short ps[4096];
  const int tid = threadIdx.x, lane = tid & 63, w = tid >> 6;
  const int hb = blockIdx.x >> 5, qb = blockIdx.x & 31;
  const size_t qkbase = ((size_t)hb * 2048 + qb * 64) * 64;
  const size_t vbase = (size_t)hb * 64 * 2048 + qb * 64;

  // stage Q, K, V^T (8 KB each); inverse-swizzled global source, linear LDS dest
  #pragma unroll
  for (int i = 0; i < 2; ++i) {
    const int G = i * 256 + tid;
    const int row = G >> 3, slot = G & 7;
    const int sg = slot ^ (row & 7);
    gld_lds16(Q + qkbase + row * 64 + sg * 8, &qs[G * 8]);
    gld_lds16(Kb + qkbase + row * 64 + sg * 8, &ks2[G * 8]);
    gld_lds16(Vt + vbase + (size_t)row * 2048 + sg * 8, &vs[G * 8]);
  }
  asm volatile("s_waitcnt vmcnt(0)" ::: "memory");
  __syncthreads();

  const int fr = lane & 15, gh = lane >> 4;
  const int arow = w * 16 + fr;   // this wave's A rows (q)

  // ---- QK^T: S[16q][64k] per wave
  s16x8 aq[2], bk[2][4];
  #pragma unroll
  for (int ks = 0; ks < 2; ++ks) {
    aq[ks] = *(const s16x8*)&qs[arow * 64 + (((ks * 4 + gh) ^ (arow & 7)) << 3)];
    #pragma unroll
    for (int nt = 0; nt < 4; ++nt) {
      const int krow = nt * 16 + fr;
      bk[ks][nt] = *(const s16x8*)&ks2[krow * 64 + (((ks * 4 + gh) ^ (krow & 7)) << 3)];
    }
  }
  f32x4 s[4] = {};
  #pragma unroll
  for (int ks = 0; ks < 2; ++ks)
    #pragma unroll
    for (int nt = 0; nt < 4; ++nt)
      s[nt] = MFMA16(aq[ks], bk[ks][nt], s[nt]);

  // ---- softmax: D row q = gh*4+j, col k = nt*16+fr -> reduce over fr's 16 lanes
  #pragma unroll
  for (int j = 0; j < 4; ++j) {
    float t0 = s[0][j] * 0.125f, t1 = s[1][j] * 0.125f;
    float t2 = s[2][j] * 0.125f, t3 = s[3][j] * 0.125f;
    float m = fmaxf(fmaxf(t0, t1), fmaxf(t2, t3));
    m = fmaxf(m, __shfl_xor(m, 1, 64));
    m = fmaxf(m, __shfl_xor(m, 2, 64));
    m = fmaxf(m, __shfl_xor(m, 4, 64));
    m = fmaxf(m, __shfl_xor(m, 8, 64));
    t0 = __expf(t0 - m); t1 = __expf(t1 - m);
    t2 = __expf(t2 - m); t3 = __expf(t3 - m);
    float sum = t0 + t1 + t2 + t3;
    sum += __shfl_xor(sum, 1, 64);
    sum += __shfl_xor(sum, 2, 64);
    sum += __shfl_xor(sum, 4, 64);
    sum += __shfl_xor(sum, 8, 64);
    const float r = 1.0f / sum;
    s[0][j] = t0 * r; s[1][j] = t1 * r; s[2][j] = t2 * r; s[3][j] = t3 * r;
  }

  // ---- P -> bf16 LDS (swizzled); wave writes/reads only its own 16 rows
  #pragma unroll
  for (int j = 0; j < 4; ++j) {
    const int q = w * 16 + gh * 4 + j;
    #pragma unroll
    for (int nt = 0; nt < 4; ++nt) {
      const int k = nt * 16 + fr;
      ps[q * 64 + (((k >> 3) ^ (q & 7)) << 3) + (k & 7)] = f2bf(s[nt][j]);
    }
  }

  // ---- PV: X[16q][64d] = P rows x V^T rows
  s16x8 ap[2], bv2[2][4];
  #pragma unroll
  for (int ks = 0; ks < 2; ++ks) {
    ap[ks] = *(const s16x8*)&ps[arow * 64 + (((ks * 4 + gh) ^ (arow & 7)) << 3)];
    #pragma unroll
    for (int nt = 0; nt < 4; ++nt) {
      const int drow = nt * 16 + fr;
      bv2[ks][nt] = *(const s16x8*)&vs[drow * 64 + (((ks * 4 + gh) ^ (drow & 7)) << 3)];
    }
  }
  f32x4 x[4] = {};
  #pragma unroll
  for (int ks = 0; ks < 2; ++ks)
    #pragma unroll
    for (int nt = 0; nt < 4; ++nt)
      x[nt] = MFMA16(ap[ks], bv2[ks][nt], x[nt]);

  // ---- write X: [b*2048 + s][h*64 + d] bf16
  const int b = hb >> 4, h = hb & 15;
  #pragma unroll
  for (int nt = 0; nt < 4; ++nt)
    #pragma unroll
    for (int j = 0; j < 4; ++j) {
      const int sgl = qb * 64 + w * 16 + gh * 4 + j;
      X[((size_t)(b * 2048 + sgl)) * 1024 + h * 64 + nt * 16 + fr] = f2bf(x[nt][j]);
    }
}

// ---------- launch ----------
extern "C" void kernel_launch(void* const* d_in, const int* in_sizes, int n_in,
                              void* d_out, int out_size, void* d_ws, size_t ws_size,
                              hipStream_t stream) {
  const float* query = (const float*)d_in[0];
  const float* key   = (const float*)d_in[1];
  const float* value = (const float*)d_in[2];
  const float* Wq = (const float*)d_in[3]; const float* bq = (const float*)d_in[4];
  const float* Wk = (const float*)d_in[5]; const float* bk = (const float*)d_in[6];
  const float* Wv = (const float*)d_in[7]; const float* bv = (const float*)d_in[8];
  const float* Wo = (const float*)d_in[9]; const float* bo = (const float*)d_in[10];
  float* out = (float*)d_out;

  const size_t W_E = 1024 * 1024;
  const size_t X_E = 4096 * 1024;
  unsigned char* p = (unsigned char*)d_ws;
  auto take = [&](size_t bytes) { void* r = (void*)p; p += bytes; return r; };

  unsigned short* wtq = (unsigned short*)take(W_E * 2);
  unsigned short* wtk = (unsigned short*)take(W_E * 2);
  unsigned short* wtv = (unsigned short*)take(W_E * 2);
  unsigned short* wto = (unsigned short*)take(W_E * 2);
  unsigned short* xq = (unsigned short*)take(X_E * 2);
  unsigned short* xk = (unsigned short*)take(X_E * 2);
  unsigned short* xv = (unsigned short*)take(X_E * 2);
  unsigned short* Qb = (unsigned short*)take(X_E * 2);
  unsigned short* Kb = (unsigned short*)take(X_E * 2);
  unsigned short* Vt = (unsigned short*)take(X_E * 2);
  unsigned short* ao = (unsigned short*)take(X_E * 2);
  (void)ws_size; (void)in_sizes; (void)n_in; (void)out_size;

  transw<<<dim3(256, 4), 256, 0, stream>>>(Wq, wtq, Wk, wtk, Wv, wtv, Wo, wto);
  convert_x3<<<dim3(4096, 3), 256, 0, stream>>>(query, xq, key, xk, value, xv);

  QkvArgs qkv = {};
  qkv.A[0] = xq; qkv.B[0] = wtq; qkv.bias[0] = bq; qkv.out[0] = Qb;
  qkv.A[1] = xk; qkv.B[1] = wtk; qkv.bias[1] = bk; qkv.out[1] = Kb;
  qkv.A[2] = xv; qkv.B[2] = wtv; qkv.bias[2] = bv; qkv.out[2] = Vt;
  gemm_qkv<<<dim3(192), 512, 0, stream>>>(qkv);

  attn_mfma<<<dim3(1024), 256, 0, stream>>>(Qb, Kb, Vt, ao);

  gemm_oproj<<<dim3(256), 256, 0, stream>>>(ao, wto, bo, out);
}

// Round 7
// 85.477 us; speedup vs baseline: 2.7382x; 1.0145x over previous
//
#include <hip/hip_runtime.h>
#include <hip/hip_bf16.h>

// ---------- helpers ----------
typedef __attribute__((ext_vector_type(4))) float f32x4;
typedef __attribute__((ext_vector_type(8))) short s16x8;

#define MFMA16(a, b, c) __builtin_amdgcn_mfma_f32_16x16x32_bf16(a, b, c, 0, 0, 0)

__device__ __forceinline__ void gld_lds16(const void* g, void* l) {
  __builtin_amdgcn_global_load_lds(
      (const __attribute__((address_space(1))) unsigned int*)g,
      (__attribute__((address_space(3))) unsigned int*)l, 16, 0, 0);
}

__device__ __forceinline__ unsigned short f2bf(float f) {
  union { __hip_bfloat16 b; unsigned short u; } cv;
  cv.b = __float2bfloat16(f);
  return cv.u;
}
__device__ __forceinline__ float bf2f(unsigned short u) {
  union { unsigned short u; __hip_bfloat16 b; } cv;
  cv.u = u;
  return __bfloat162float(cv.b);
}

// ---------- kernel 1: W [K][N] f32 -> W^T [N][K] bf16 ----------
__global__ void transw(const float* W0, unsigned short* H0,
                       const float* W1, unsigned short* H1,
                       const float* W2, unsigned short* H2,
                       const float* W3, unsigned short* H3) {
  __shared__ float tile[64 * 65];
  const float* W; unsigned short* H;
  switch (blockIdx.y) {
    case 0: W = W0; H = H0; break;
    case 1: W = W1; H = H1; break;
    case 2: W = W2; H = H2; break;
    default: W = W3; H = H3; break;
  }
  const int t = threadIdx.x;
  const int tk0 = (blockIdx.x & 15) * 64;   // k tile
  const int tn0 = (blockIdx.x >> 4) * 64;   // n tile
  for (int i = 0; i < 16; ++i) {
    int idx = i * 256 + t;
    int r = idx >> 6, c = idx & 63;
    tile[r * 65 + c] = W[(size_t)(tk0 + r) * 1024 + tn0 + c];
  }
  __syncthreads();
  for (int i = 0; i < 16; ++i) {
    int idx = i * 256 + t;
    int r = idx >> 6, c = idx & 63;   // r: n offset, c: k offset
    H[(size_t)(tn0 + r) * 1024 + tk0 + c] = f2bf(tile[c * 65 + r]);
  }
}

// ---------- kernel 2: X [4096][1024] f32 -> bf16 ----------
__global__ void convert_x3(const float* A0, unsigned short* H0,
                           const float* A1, unsigned short* H1,
                           const float* A2, unsigned short* H2) {
  const float* src; unsigned short* h;
  switch (blockIdx.y) {
    case 0: src = A0; h = H0; break;
    case 1: src = A1; h = H1; break;
    default: src = A2; h = H2; break;
  }
  int i = blockIdx.x * 256 + threadIdx.x;   // float4 index
  float4 v = ((const float4*)src)[i];
  ((ushort4*)h)[i] = make_ushort4(f2bf(v.x), f2bf(v.y), f2bf(v.z), f2bf(v.w));
}

// ---------- kernel 3a: QKV bf16 GEMM, 256x256 tile, 8 waves ----------
// Phase-split schedule: per BK=32 step, 2 phases x 16 MFMA with interleaved
// ds_read / stage issue; counted vmcnt(8) (depth-3 prefetch, 4 LDS bufs).
// g==0,1 (Q,K): out [b*16+h][s][64]. g==2 (V): out TRANSPOSED [b*16+h][d][2048 s].
struct QkvArgs {
  const unsigned short* A[3];
  const unsigned short* B[3];
  const float* bias[3];
  unsigned short* out[3];
};

__global__ __launch_bounds__(512, 2)
void gemm_qkv(QkvArgs args) {
  const int K = 1024;
  __shared__ __align__(16) unsigned short lds[4][2][8192];   // 128 KB
  const int tid = threadIdx.x;
  const int lane = tid & 63, w = tid >> 6;

  // XCD-aware bijective swizzle (192 % 8 == 0)
  const int nwg = 192;
  const int orig = blockIdx.x;
  const int swz = (orig & 7) * (nwg >> 3) + (orig >> 3);
  const int g = swz >> 6;          // 64 blocks per gemm (16 M x 4 N)
  const int tl = swz & 63;
  const int m0 = (tl >> 2) * 256, n0 = (tl & 3) * 256;

  const unsigned short* A = args.A[g];
  const unsigned short* B = args.B[g];
  const float* bias = args.bias[g];
  unsigned short* out = args.out[g];

  const int wm = (w >> 2) * 128, wn = (w & 3) * 64;   // wave tile 128x64
  const int fr = lane & 15, gh = lane >> 4;

  // staging sources: pair-packed granule layout (see R4), 2 granules/thread/matrix
  size_t aoff[2], boff[2]; int dst[2];
  #pragma unroll
  for (int i = 0; i < 2; ++i) {
    const int G = i * 512 + tid;
    const int rp = G >> 3, spr = G & 7;
    const int s = spr ^ (rp & 7);
    const int srow = 2 * rp + (s >> 2), ko = (s & 3) * 8;
    aoff[i] = (size_t)(m0 + srow) * K + ko;
    boff[i] = (size_t)(n0 + srow) * K + ko;
    dst[i] = G * 8;
  }

  auto stageA = [&](int buf, int kt) {
    gld_lds16(A + aoff[0] + kt, &lds[buf][0][dst[0]]);
    gld_lds16(A + aoff[1] + kt, &lds[buf][0][dst[1]]);
  };
  auto stageB = [&](int buf, int kt) {
    gld_lds16(B + boff[0] + kt, &lds[buf][1][dst[0]]);
    gld_lds16(B + boff[1] + kt, &lds[buf][1][dst[1]]);
  };

  f32x4 acc[8][4] = {};
  const int laneoff = (fr >> 1) * 64 + ((((fr & 1) << 2) | gh) ^ (fr >> 1)) * 8;

  // prologue: stage steps 0..2 (12 loads), gate step 0
  stageA(0, 0);  stageB(0, 0);
  stageA(1, 32); stageB(1, 32);
  stageA(2, 64); stageB(2, 64);
  asm volatile("s_waitcnt vmcnt(8)" ::: "memory");
  __builtin_amdgcn_s_barrier();
  __builtin_amdgcn_sched_barrier(0);

  #pragma unroll 1
  for (int t = 0; t < 32; ++t) {
    const int buf = t & 3;
    const unsigned short* La = &lds[buf][0][wm * 32 + laneoff];
    const unsigned short* Lb = &lds[buf][1][wn * 32 + laneoff];
    s16x8 a[8], b[4];

    // ---- phase 0: B frags + A frags 0-3; stage A(t+3); 16 MFMA
    #pragma unroll
    for (int nt = 0; nt < 4; ++nt) b[nt] = *(const s16x8*)&Lb[nt * 512];
    #pragma unroll
    for (int mt = 0; mt < 4; ++mt) a[mt] = *(const s16x8*)&La[mt * 512];
    if (t <= 28) stageA((t + 3) & 3, (t + 3) * 32);
    __builtin_amdgcn_s_barrier();
    asm volatile("s_waitcnt lgkmcnt(0)" ::: "memory");
    __builtin_amdgcn_sched_barrier(0);
    __builtin_amdgcn_s_setprio(1);
    #pragma unroll
    for (int mt = 0; mt < 4; ++mt)
      #pragma unroll
      for (int nt = 0; nt < 4; ++nt)
        acc[mt][nt] = MFMA16(a[mt], b[nt], acc[mt][nt]);
    __builtin_amdgcn_s_setprio(0);
    __builtin_amdgcn_s_barrier();
    __builtin_amdgcn_sched_barrier(0);

    // ---- phase 1: A frags 4-7; stage B(t+3); 16 MFMA; counted vmcnt
    #pragma unroll
    for (int mt = 4; mt < 8; ++mt) a[mt] = *(const s16x8*)&La[mt * 512];
    if (t <= 28) stageB((t + 3) & 3, (t + 3) * 32);
    __builtin_amdgcn_s_barrier();
    asm volatile("s_waitcnt lgkmcnt(0)" ::: "memory");
    __builtin_amdgcn_sched_barrier(0);
    __builtin_amdgcn_s_setprio(1);
    #pragma unroll
    for (int mt = 4; mt < 8; ++mt)
      #pragma unroll
      for (int nt = 0; nt < 4; ++nt)
        acc[mt][nt] = MFMA16(a[mt], b[nt], acc[mt][nt]);
    __builtin_amdgcn_s_setprio(0);
    if (t < 29)       { asm volatile("s_waitcnt vmcnt(8)" ::: "memory"); }
    else if (t == 29) { asm volatile("s_waitcnt vmcnt(4)" ::: "memory"); }
    else if (t == 30) { asm volatile("s_waitcnt vmcnt(0)" ::: "memory"); }
    __builtin_amdgcn_s_barrier();
    __builtin_amdgcn_sched_barrier(0);
  }

  // epilogue: C/D layout col = lane&15, row = (lane>>4)*4 + j
  float bv[4];
  #pragma unroll
  for (int nt = 0; nt < 4; ++nt) bv[nt] = bias[n0 + wn + nt * 16 + fr];
  if (g == 2) {
    // V transposed: [b*16+h][d][2048 s]; 4 consecutive s rows pack to ushort4
    #pragma unroll
    for (int mt = 0; mt < 8; ++mt) {
      const int gm = m0 + wm + mt * 16 + (gh << 2);   // s base (mult of 4)
      const int b2 = gm >> 11, s = gm & 2047;
      #pragma unroll
      for (int nt = 0; nt < 4; ++nt) {
        const int gn = n0 + wn + nt * 16 + fr;
        const int h = gn >> 6, d = gn & 63;
        f32x4 r = acc[mt][nt];
        ushort4 w4 = make_ushort4(f2bf(r[0] + bv[nt]), f2bf(r[1] + bv[nt]),
                                  f2bf(r[2] + bv[nt]), f2bf(r[3] + bv[nt]));
        *(ushort4*)&out[((size_t)((b2 * 16 + h) * 64 + d)) * 2048 + s] = w4;
      }
    }
  } else {
    #pragma unroll
    for (int mt = 0; mt < 8; ++mt) {
      const int gm = m0 + wm + mt * 16 + (gh << 2);
      #pragma unroll
      for (int nt = 0; nt < 4; ++nt) {
        const int gn = n0 + wn + nt * 16 + fr;
        f32x4 r = acc[mt][nt];
        #pragma unroll
        for (int j = 0; j < 4; ++j) {
          const int row = gm + j;
          size_t off = (((size_t)((row >> 11) * 16 + (gn >> 6))) * 2048 + (row & 2047)) * 64 + (gn & 63);
          out[off] = f2bf(r[j] + bv[nt]);
        }
      }
    }
  }
}

// ---------- kernel 3b: O-proj bf16 GEMM, 128x128 tile, 4 waves, depth-3 ----------
__global__ __launch_bounds__(256, 3)
void gemm_oproj(const unsigned short* __restrict__ A, const unsigned short* __restrict__ B,
                const float* __restrict__ bias, float* __restrict__ out) {
  const int K = 1024, N = 1024;
  __shared__ __align__(16) unsigned short lds[3][2][4096];   // 48 KB
  const int tid = threadIdx.x;
  const int lane = tid & 63, wid = tid >> 6;

  const int nwg = 256;
  const int orig = blockIdx.x;
  const int swz = (orig & 7) * (nwg >> 3) + (orig >> 3);
  const int m0 = (swz >> 3) * 128, n0 = (swz & 7) * 128;

  const int wm = (wid >> 1) * 64, wn = (wid & 1) * 64;
  const int fr = lane & 15, gh = lane >> 4;

  size_t aoff[2], boff[2]; int dst[2];
  #pragma unroll
  for (int i = 0; i < 2; ++i) {
    const int G = i * 256 + tid;
    const int rp = G >> 3, spr = G & 7;
    const int s = spr ^ (rp & 7);
    const int srow = 2 * rp + (s >> 2), ko = (s & 3) * 8;
    aoff[i] = (size_t)(m0 + srow) * K + ko;
    boff[i] = (size_t)(n0 + srow) * K + ko;
    dst[i] = G * 8;
  }

  auto stage = [&](int buf, int kt) {
    #pragma unroll
    for (int i = 0; i < 2; ++i) {
      gld_lds16(A + aoff[i] + kt, &lds[buf][0][dst[i]]);
      gld_lds16(B + boff[i] + kt, &lds[buf][1][dst[i]]);
    }
  };

  f32x4 acc[4][4] = {};
  const int laneoff = (fr >> 1) * 64 + ((((fr & 1) << 2) | gh) ^ (fr >> 1)) * 8;

  // prologue: stage steps 0,1; gate step 0
  stage(0, 0); stage(1, 32);
  asm volatile("s_waitcnt vmcnt(4)" ::: "memory");
  __builtin_amdgcn_s_barrier();
  __builtin_amdgcn_sched_barrier(0);

  #pragma unroll 1
  for (int t = 0; t < 32; ++t) {
    const int buf = t % 3;
    const unsigned short* La = &lds[buf][0][wm * 32 + laneoff];
    const unsigned short* Lb = &lds[buf][1][wn * 32 + laneoff];
    s16x8 b[4], a[4];
    #pragma unroll
    for (int nt = 0; nt < 4; ++nt) b[nt] = *(const s16x8*)&Lb[nt * 512];
    #pragma unroll
    for (int mt = 0; mt < 4; ++mt) a[mt] = *(const s16x8*)&La[mt * 512];
    if (t <= 29) stage((t + 2) % 3, (t + 2) * 32);
    __builtin_amdgcn_s_barrier();
    asm volatile("s_waitcnt lgkmcnt(0)" ::: "memory");
    __builtin_amdgcn_sched_barrier(0);
    __builtin_amdgcn_s_setprio(1);
    #pragma unroll
    for (int mt = 0; mt < 4; ++mt)
      #pragma unroll
      for (int nt = 0; nt < 4; ++nt)
        acc[mt][nt] = MFMA16(a[mt], b[nt], acc[mt][nt]);
    __builtin_amdgcn_s_setprio(0);
    if (t < 30)       { asm volatile("s_waitcnt vmcnt(4)" ::: "memory"); }
    else if (t == 30) { asm volatile("s_waitcnt vmcnt(0)" ::: "memory"); }
    __builtin_amdgcn_s_barrier();
    __builtin_amdgcn_sched_barrier(0);
  }

  #pragma unroll
  for (int mt = 0; mt < 4; ++mt) {
    const int gm = m0 + wm + mt * 16 + (gh << 2);
    #pragma unroll
    for (int nt = 0; nt < 4; ++nt) {
      const int gn = n0 + wn + nt * 16 + fr;
      const float bvv = bias[gn];
      f32x4 r = acc[mt][nt];
      #pragma unroll
      for (int j = 0; j < 4; ++j)
        out[(size_t)(gm + j) * N + gn] = r[j] + bvv;
    }
  }
}

// ---------- kernel 4: block-diagonal attention, MFMA core ----------
// grid 1024 = hb*32 + qb. Q,K: [hb][2048 s][64 d] bf16. Vt: [hb][64 d][2048 s] bf16.
// LDS tiles [64][64] bf16 with granule-XOR: granule g of row r stored at slot g^(r&7).
__global__ __launch_bounds__(256, 2)
void attn_mfma(const unsigned short* __restrict__ Q, const unsigned short* __restrict__ Kb,
               const unsigned short* __restrict__ Vt, unsigned short* __restrict__ X) {
  __shared__ __align__(16) unsigned short qs[4096];
  __shared__ __align__(16) unsigned short ks2[4096];
  __shared__ __align__(16) unsigned short vs[4096];
  __shared__ __align__(16) unsigned short ps[4096];
  const int tid = threadIdx.x, lane = tid & 63, w = tid >> 6;
  const int hb = blockIdx.x >> 5, qb = blockIdx.x & 31;
  const size_t qkbase = ((size_t)hb * 2048 + qb * 64) * 64;
  const size_t vbase = (size_t)hb * 64 * 2048 + qb * 64;

  // stage Q, K, V^T (8 KB each); inverse-swizzled global source, linear LDS dest
  #pragma unroll
  for (int i = 0; i < 2; ++i) {
    const int G = i * 256 + tid;
    const int row = G >> 3, slot = G & 7;
    const int sg = slot ^ (row & 7);
    gld_lds16(Q + qkbase + row * 64 + sg * 8, &qs[G * 8]);
    gld_lds16(Kb + qkbase + row * 64 + sg * 8, &ks2[G * 8]);
    gld_lds16(Vt + vbase + (size_t)row * 2048 + sg * 8, &vs[G * 8]);
  }
  asm volatile("s_waitcnt vmcnt(0)" ::: "memory");
  __syncthreads();

  const int fr = lane & 15, gh = lane >> 4;
  const int arow = w * 16 + fr;   // this wave's A rows (q)

  // ---- QK^T: S[16q][64k] per wave
  s16x8 aq[2], bk[2][4];
  #pragma unroll
  for (int ks = 0; ks < 2; ++ks) {
    aq[ks] = *(const s16x8*)&qs[arow * 64 + (((ks * 4 + gh) ^ (arow & 7)) << 3)];
    #pragma unroll
    for (int nt = 0; nt < 4; ++nt) {
      const int krow = nt * 16 + fr;
      bk[ks][nt] = *(const s16x8*)&ks2[krow * 64 + (((ks * 4 + gh) ^ (krow & 7)) << 3)];
    }
  }
  f32x4 s[4] = {};
  #pragma unroll
  for (int ks = 0; ks < 2; ++ks)
    #pragma unroll
    for (int nt = 0; nt < 4; ++nt)
      s[nt] = MFMA16(aq[ks], bk[ks][nt], s[nt]);

  // ---- softmax: D row q = gh*4+j, col k = nt*16+fr -> reduce over fr's 16 lanes
  #pragma unroll
  for (int j = 0; j < 4; ++j) {
    float t0 = s[0][j] * 0.125f, t1 = s[1][j] * 0.125f;
    float t2 = s[2][j] * 0.125f, t3 = s[3][j] * 0.125f;
    float m = fmaxf(fmaxf(t0, t1), fmaxf(t2, t3));
    m = fmaxf(m, __shfl_xor(m, 1, 64));
    m = fmaxf(m, __shfl_xor(m, 2, 64));
    m = fmaxf(m, __shfl_xor(m, 4, 64));
    m = fmaxf(m, __shfl_xor(m, 8, 64));
    t0 = __expf(t0 - m); t1 = __expf(t1 - m);
    t2 = __expf(t2 - m); t3 = __expf(t3 - m);
    float sum = t0 + t1 + t2 + t3;
    sum += __shfl_xor(sum, 1, 64);
    sum += __shfl_xor(sum, 2, 64);
    sum += __shfl_xor(sum, 4, 64);
    sum += __shfl_xor(sum, 8, 64);
    const float r = 1.0f / sum;
    s[0][j] = t0 * r; s[1][j] = t1 * r; s[2][j] = t2 * r; s[3][j] = t3 * r;
  }

  // ---- P -> bf16 LDS (swizzled); wave writes/reads only its own 16 rows
  #pragma unroll
  for (int j = 0; j < 4; ++j) {
    const int q = w * 16 + gh * 4 + j;
    #pragma unroll
    for (int nt = 0; nt < 4; ++nt) {
      const int k = nt * 16 + fr;
      ps[q * 64 + (((k >> 3) ^ (q & 7)) << 3) + (k & 7)] = f2bf(s[nt][j]);
    }
  }

  // ---- PV: X[16q][64d] = P rows x V^T rows
  s16x8 ap[2], bv2[2][4];
  #pragma unroll
  for (int ks = 0; ks < 2; ++ks) {
    ap[ks] = *(const s16x8*)&ps[arow * 64 + (((ks * 4 + gh) ^ (arow & 7)) << 3)];
    #pragma unroll
    for (int nt = 0; nt < 4; ++nt) {
      const int drow = nt * 16 + fr;
      bv2[ks][nt] = *(const s16x8*)&vs[drow * 64 + (((ks * 4 + gh) ^ (drow & 7)) << 3)];
    }
  }
  f32x4 x[4] = {};
  #pragma unroll
  for (int ks = 0; ks < 2; ++ks)
    #pragma unroll
    for (int nt = 0; nt < 4; ++nt)
      x[nt] = MFMA16(ap[ks], bv2[ks][nt], x[nt]);

  // ---- write X: [b*2048 + s][h*64 + d] bf16
  const int b = hb >> 4, h = hb & 15;
  #pragma unroll
  for (int nt = 0; nt < 4; ++nt)
    #pragma unroll
    for (int j = 0; j < 4; ++j) {
      const int sgl = qb * 64 + w * 16 + gh * 4 + j;
      X[((size_t)(b * 2048 + sgl)) * 1024 + h * 64 + nt * 16 + fr] = f2bf(x[nt][j]);
    }
}

// ---------- launch ----------
extern "C" void kernel_launch(void* const* d_in, const int* in_sizes, int n_in,
                              void* d_out, int out_size, void* d_ws, size_t ws_size,
                              hipStream_t stream) {
  const float* query = (const float*)d_in[0];
  const float* key   = (const float*)d_in[1];
  const float* value = (const float*)d_in[2];
  const float* Wq = (const float*)d_in[3]; const float* bq = (const float*)d_in[4];
  const float* Wk = (const float*)d_in[5]; const float* bk = (const float*)d_in[6];
  const float* Wv = (const float*)d_in[7]; const float* bv = (const float*)d_in[8];
  const float* Wo = (const float*)d_in[9]; const float* bo = (const float*)d_in[10];
  float* out = (float*)d_out;

  const size_t W_E = 1024 * 1024;
  const size_t X_E = 4096 * 1024;
  unsigned char* p = (unsigned char*)d_ws;
  auto take = [&](size_t bytes) { void* r = (void*)p; p += bytes; return r; };

  unsigned short* wtq = (unsigned short*)take(W_E * 2);
  unsigned short* wtk = (unsigned short*)take(W_E * 2);
  unsigned short* wtv = (unsigned short*)take(W_E * 2);
  unsigned short* wto = (unsigned short*)take(W_E * 2);
  unsigned short* xq = (unsigned short*)take(X_E * 2);
  unsigned short* xk = (unsigned short*)take(X_E * 2);
  unsigned short* xv = (unsigned short*)take(X_E * 2);
  unsigned short* Qb = (unsigned short*)take(X_E * 2);
  unsigned short* Kb = (unsigned short*)take(X_E * 2);
  unsigned short* Vt = (unsigned short*)take(X_E * 2);
  unsigned short* ao = (unsigned short*)take(X_E * 2);
  (void)ws_size; (void)in_sizes; (void)n_in; (void)out_size;

  transw<<<dim3(256, 4), 256, 0, stream>>>(Wq, wtq, Wk, wtk, Wv, wtv, Wo, wto);
  convert_x3<<<dim3(4096, 3), 256, 0, stream>>>(query, xq, key, xk, value, xv);

  QkvArgs qkv = {};
  qkv.A[0] = xq; qkv.B[0] = wtq; qkv.bias[0] = bq; qkv.out[0] = Qb;
  qkv.A[1] = xk; qkv.B[1] = wtk; qkv.bias[1] = bk; qkv.out[1] = Kb;
  qkv.A[2] = xv; qkv.B[2] = wtv; qkv.bias[2] = bv; qkv.out[2] = Vt;
  gemm_qkv<<<dim3(192), 512, 0, stream>>>(qkv);

  attn_mfma<<<dim3(1024), 256, 0, stream>>>(Qb, Kb, Vt, ao);

  gemm_oproj<<<dim3(256), 256, 0, stream>>>(ao, wto, bo, out);
}

// Round 8
// 79.792 us; speedup vs baseline: 2.9333x; 1.0713x over previous
//
#include <hip/hip_runtime.h>
#include <hip/hip_bf16.h>

// ---------- helpers ----------
typedef __attribute__((ext_vector_type(4))) float f32x4;
typedef __attribute__((ext_vector_type(8))) short s16x8;

#define MFMA16(a, b, c) __builtin_amdgcn_mfma_f32_16x16x32_bf16(a, b, c, 0, 0, 0)

__device__ __forceinline__ void gld_lds16(const void* g, void* l) {
  __builtin_amdgcn_global_load_lds(
      (const __attribute__((address_space(1))) unsigned int*)g,
      (__attribute__((address_space(3))) unsigned int*)l, 16, 0, 0);
}

__device__ __forceinline__ unsigned short f2bf(float f) {
  union { __hip_bfloat16 b; unsigned short u; } cv;
  cv.b = __float2bfloat16(f);
  return cv.u;
}
__device__ __forceinline__ float bf2f(unsigned short u) {
  union { unsigned short u; __hip_bfloat16 b; } cv;
  cv.u = u;
  return __bfloat162float(cv.b);
}

// ---------- kernel 1: W [K][N] f32 -> W^T [N][K] bf16 ----------
__global__ void transw(const float* W0, unsigned short* H0,
                       const float* W1, unsigned short* H1,
                       const float* W2, unsigned short* H2,
                       const float* W3, unsigned short* H3) {
  __shared__ float tile[64 * 65];
  const float* W; unsigned short* H;
  switch (blockIdx.y) {
    case 0: W = W0; H = H0; break;
    case 1: W = W1; H = H1; break;
    case 2: W = W2; H = H2; break;
    default: W = W3; H = H3; break;
  }
  const int t = threadIdx.x;
  const int tk0 = (blockIdx.x & 15) * 64;   // k tile
  const int tn0 = (blockIdx.x >> 4) * 64;   // n tile
  for (int i = 0; i < 16; ++i) {
    int idx = i * 256 + t;
    int r = idx >> 6, c = idx & 63;
    tile[r * 65 + c] = W[(size_t)(tk0 + r) * 1024 + tn0 + c];
  }
  __syncthreads();
  for (int i = 0; i < 16; ++i) {
    int idx = i * 256 + t;
    int r = idx >> 6, c = idx & 63;   // r: n offset, c: k offset
    H[(size_t)(tn0 + r) * 1024 + tk0 + c] = f2bf(tile[c * 65 + r]);
  }
}

// ---------- kernel 2: X [4096][1024] f32 -> bf16 ----------
__global__ void convert_x3(const float* A0, unsigned short* H0,
                           const float* A1, unsigned short* H1,
                           const float* A2, unsigned short* H2) {
  const float* src; unsigned short* h;
  switch (blockIdx.y) {
    case 0: src = A0; h = H0; break;
    case 1: src = A1; h = H1; break;
    default: src = A2; h = H2; break;
  }
  int i = blockIdx.x * 256 + threadIdx.x;   // float4 index
  float4 v = ((const float4*)src)[i];
  ((ushort4*)h)[i] = make_ushort4(f2bf(v.x), f2bf(v.y), f2bf(v.z), f2bf(v.w));
}

// ---------- kernel 3a: QKV bf16 GEMM, 256x256 tile, 8 waves, depth-4 ----------
// SINGLE barrier per BK=32 step: {ds_reads; stage(t+3); MFMA x32 (compiler
// lgkm waits); counted vmcnt; s_barrier}. Epilogue via LDS transpose.
// g==0,1 (Q,K): out [b*16+h][s][64]. g==2 (V): out TRANSPOSED [b*16+h][d][2048 s].
struct QkvArgs {
  const unsigned short* A[3];
  const unsigned short* B[3];
  const float* bias[3];
  unsigned short* out[3];
};

__global__ __launch_bounds__(512, 2)
void gemm_qkv(QkvArgs args) {
  const int K = 1024;
  __shared__ __align__(16) unsigned short lds[4][2][8192];   // 128 KB
  const int tid = threadIdx.x;
  const int lane = tid & 63, w = tid >> 6;

  // XCD-aware bijective swizzle (192 % 8 == 0)
  const int nwg = 192;
  const int orig = blockIdx.x;
  const int swz = (orig & 7) * (nwg >> 3) + (orig >> 3);
  const int g = swz >> 6;          // 64 blocks per gemm (16 M x 4 N)
  const int tl = swz & 63;
  const int m0 = (tl >> 2) * 256, n0 = (tl & 3) * 256;

  const unsigned short* A = args.A[g];
  const unsigned short* B = args.B[g];
  const float* bias = args.bias[g];
  unsigned short* out = args.out[g];

  const int wm = (w >> 2) * 128, wn = (w & 3) * 64;   // wave tile 128x64
  const int fr = lane & 15, gh = lane >> 4;

  // staging sources: pair-packed granule layout, 2 granules/thread/matrix
  size_t aoff[2], boff[2]; int dst[2];
  #pragma unroll
  for (int i = 0; i < 2; ++i) {
    const int G = i * 512 + tid;
    const int rp = G >> 3, spr = G & 7;
    const int s = spr ^ (rp & 7);
    const int srow = 2 * rp + (s >> 2), ko = (s & 3) * 8;
    aoff[i] = (size_t)(m0 + srow) * K + ko;
    boff[i] = (size_t)(n0 + srow) * K + ko;
    dst[i] = G * 8;
  }

  auto stage = [&](int buf, int kt) {
    gld_lds16(A + aoff[0] + kt, &lds[buf][0][dst[0]]);
    gld_lds16(A + aoff[1] + kt, &lds[buf][0][dst[1]]);
    gld_lds16(B + boff[0] + kt, &lds[buf][1][dst[0]]);
    gld_lds16(B + boff[1] + kt, &lds[buf][1][dst[1]]);
  };

  f32x4 acc[8][4] = {};
  const int laneoff = (fr >> 1) * 64 + ((((fr & 1) << 2) | gh) ^ (fr >> 1)) * 8;

  // prologue: stage steps 0..2
  stage(0, 0); stage(1, 32); stage(2, 64);
  asm volatile("s_waitcnt vmcnt(8)" ::: "memory");
  __builtin_amdgcn_s_barrier();
  __builtin_amdgcn_sched_barrier(0);

  #pragma unroll 1
  for (int t = 0; t < 32; ++t) {
    const int buf = t & 3;
    const unsigned short* La = &lds[buf][0][wm * 32 + laneoff];
    const unsigned short* Lb = &lds[buf][1][wn * 32 + laneoff];
    s16x8 a[8], b[4];
    #pragma unroll
    for (int nt = 0; nt < 4; ++nt) b[nt] = *(const s16x8*)&Lb[nt * 512];
    #pragma unroll
    for (int mt = 0; mt < 8; ++mt) a[mt] = *(const s16x8*)&La[mt * 512];
    if (t <= 28) stage((t + 3) & 3, (t + 3) * 32);
    __builtin_amdgcn_s_setprio(1);
    #pragma unroll
    for (int mt = 0; mt < 8; ++mt)
      #pragma unroll
      for (int nt = 0; nt < 4; ++nt)
        acc[mt][nt] = MFMA16(a[mt], b[nt], acc[mt][nt]);
    __builtin_amdgcn_s_setprio(0);
    if (t < 29)       { asm volatile("s_waitcnt vmcnt(8)" ::: "memory"); }
    else if (t == 29) { asm volatile("s_waitcnt vmcnt(4)" ::: "memory"); }
    else if (t == 30) { asm volatile("s_waitcnt vmcnt(0)" ::: "memory"); }
    __builtin_amdgcn_s_barrier();
    __builtin_amdgcn_sched_barrier(0);
  }

  // ---- epilogue: acc -> LDS (256x256 bf16) -> coalesced 16B stores
  float bv[4];
  #pragma unroll
  for (int nt = 0; nt < 4; ++nt) bv[nt] = bias[n0 + wn + nt * 16 + fr];
  unsigned short* eb = &lds[0][0][0];   // 65536 shorts = 256 x 256
  __syncthreads();
  if (g == 2) {
    // V: store with column XOR-swizzle so the s-major re-read is conflict-light
    #pragma unroll
    for (int mt = 0; mt < 8; ++mt)
      #pragma unroll
      for (int nt = 0; nt < 4; ++nt) {
        const int nl = wn + nt * 16 + fr;
        f32x4 r = acc[mt][nt];
        #pragma unroll
        for (int j = 0; j < 4; ++j) {
          const int sl = wm + mt * 16 + gh * 4 + j;
          eb[sl * 256 + (nl ^ ((sl >> 3) & 31))] = f2bf(r[j] + bv[nt]);
        }
      }
  } else {
    #pragma unroll
    for (int mt = 0; mt < 8; ++mt)
      #pragma unroll
      for (int nt = 0; nt < 4; ++nt) {
        const int nl = wn + nt * 16 + fr;
        f32x4 r = acc[mt][nt];
        #pragma unroll
        for (int j = 0; j < 4; ++j) {
          const int sl = wm + mt * 16 + gh * 4 + j;
          eb[sl * 256 + nl] = f2bf(r[j] + bv[nt]);
        }
      }
  }
  __syncthreads();
  const int b2 = m0 >> 11;
  if (g == 2) {
    // out[b*16+h][d][2048 s]: thread copies 8 shorts along s (16B store)
    #pragma unroll
    for (int it = 0; it < 16; ++it) {
      const int u = it * 512 + tid;
      const int nl = u >> 5, sc = u & 31;
      s16x8 v;
      #pragma unroll
      for (int r = 0; r < 8; ++r)
        v[r] = (short)eb[(sc * 8 + r) * 256 + (nl ^ sc)];
      const int gn = n0 + nl, h = gn >> 6, d = gn & 63;
      *(s16x8*)&out[((size_t)((b2 * 16 + h) * 64 + d)) * 2048 + (m0 & 2047) + sc * 8] = v;
    }
  } else {
    // out[b*16+h][s][64]: thread copies 8 shorts along d (16B store)
    #pragma unroll
    for (int it = 0; it < 16; ++it) {
      const int u = it * 512 + tid;
      const int sl = u >> 5, n8 = (u & 31) * 8;
      s16x8 v = *(const s16x8*)&eb[sl * 256 + n8];
      const int s = m0 + sl;
      const int gn = n0 + n8, h = gn >> 6, d = gn & 63;
      *(s16x8*)&out[(((size_t)(b2 * 16 + h)) * 2048 + (s & 2047)) * 64 + d] = v;
    }
  }
}

// ---------- kernel 3b: O-proj bf16 GEMM, 128x128 tile, 4 waves, depth-3 ----------
__global__ __launch_bounds__(256, 3)
void gemm_oproj(const unsigned short* __restrict__ A, const unsigned short* __restrict__ B,
                const float* __restrict__ bias, float* __restrict__ out) {
  const int K = 1024, N = 1024;
  __shared__ __align__(16) unsigned short lds[3][2][4096];   // 48 KB
  const int tid = threadIdx.x;
  const int lane = tid & 63, wid = tid >> 6;

  const int nwg = 256;
  const int orig = blockIdx.x;
  const int swz = (orig & 7) * (nwg >> 3) + (orig >> 3);
  const int m0 = (swz >> 3) * 128, n0 = (swz & 7) * 128;

  const int wm = (wid >> 1) * 64, wn = (wid & 1) * 64;
  const int fr = lane & 15, gh = lane >> 4;

  size_t aoff[2], boff[2]; int dst[2];
  #pragma unroll
  for (int i = 0; i < 2; ++i) {
    const int G = i * 256 + tid;
    const int rp = G >> 3, spr = G & 7;
    const int s = spr ^ (rp & 7);
    const int srow = 2 * rp + (s >> 2), ko = (s & 3) * 8;
    aoff[i] = (size_t)(m0 + srow) * K + ko;
    boff[i] = (size_t)(n0 + srow) * K + ko;
    dst[i] = G * 8;
  }

  auto stage = [&](int buf, int kt) {
    #pragma unroll
    for (int i = 0; i < 2; ++i) {
      gld_lds16(A + aoff[i] + kt, &lds[buf][0][dst[i]]);
      gld_lds16(B + boff[i] + kt, &lds[buf][1][dst[i]]);
    }
  };

  f32x4 acc[4][4] = {};
  const int laneoff = (fr >> 1) * 64 + ((((fr & 1) << 2) | gh) ^ (fr >> 1)) * 8;

  stage(0, 0); stage(1, 32);
  asm volatile("s_waitcnt vmcnt(4)" ::: "memory");
  __builtin_amdgcn_s_barrier();
  __builtin_amdgcn_sched_barrier(0);

  #pragma unroll 1
  for (int t = 0; t < 32; ++t) {
    const int buf = t % 3;
    const unsigned short* La = &lds[buf][0][wm * 32 + laneoff];
    const unsigned short* Lb = &lds[buf][1][wn * 32 + laneoff];
    s16x8 b[4], a[4];
    #pragma unroll
    for (int nt = 0; nt < 4; ++nt) b[nt] = *(const s16x8*)&Lb[nt * 512];
    #pragma unroll
    for (int mt = 0; mt < 4; ++mt) a[mt] = *(const s16x8*)&La[mt * 512];
    if (t <= 29) stage((t + 2) % 3, (t + 2) * 32);
    __builtin_amdgcn_s_setprio(1);
    #pragma unroll
    for (int mt = 0; mt < 4; ++mt)
      #pragma unroll
      for (int nt = 0; nt < 4; ++nt)
        acc[mt][nt] = MFMA16(a[mt], b[nt], acc[mt][nt]);
    __builtin_amdgcn_s_setprio(0);
    if (t < 30)       { asm volatile("s_waitcnt vmcnt(4)" ::: "memory"); }
    else if (t == 30) { asm volatile("s_waitcnt vmcnt(0)" ::: "memory"); }
    __builtin_amdgcn_s_barrier();
    __builtin_amdgcn_sched_barrier(0);
  }

  #pragma unroll
  for (int mt = 0; mt < 4; ++mt) {
    const int gm = m0 + wm + mt * 16 + (gh << 2);
    #pragma unroll
    for (int nt = 0; nt < 4; ++nt) {
      const int gn = n0 + wn + nt * 16 + fr;
      const float bvv = bias[gn];
      f32x4 r = acc[mt][nt];
      #pragma unroll
      for (int j = 0; j < 4; ++j)
        out[(size_t)(gm + j) * N + gn] = r[j] + bvv;
    }
  }
}

// ---------- kernel 4: block-diagonal attention, MFMA core ----------
// grid 1024 = hb*32 + qb. Q,K: [hb][2048 s][64 d] bf16. Vt: [hb][64 d][2048 s] bf16.
// LDS tiles [64][64] bf16 with granule-XOR: granule g of row r stored at slot g^(r&7).
__global__ __launch_bounds__(256, 2)
void attn_mfma(const unsigned short* __restrict__ Q, const unsigned short* __restrict__ Kb,
               const unsigned short* __restrict__ Vt, unsigned short* __restrict__ X) {
  __shared__ __align__(16) unsigned short qs[4096];
  __shared__ __align__(16) unsigned short ks2[4096];
  __shared__ __align__(16) unsigned short vs[4096];
  __shared__ __align__(16) unsigned short ps[4096];
  const int tid = threadIdx.x, lane = tid & 63, w = tid >> 6;
  const int hb = blockIdx.x >> 5, qb = blockIdx.x & 31;
  const size_t qkbase = ((size_t)hb * 2048 + qb * 64) * 64;
  const size_t vbase = (size_t)hb * 64 * 2048 + qb * 64;

  // stage Q, K, V^T (8 KB each); inverse-swizzled global source, linear LDS dest
  #pragma unroll
  for (int i = 0; i < 2; ++i) {
    const int G = i * 256 + tid;
    const int row = G >> 3, slot = G & 7;
    const int sg = slot ^ (row & 7);
    gld_lds16(Q + qkbase + row * 64 + sg * 8, &qs[G * 8]);
    gld_lds16(Kb + qkbase + row * 64 + sg * 8, &ks2[G * 8]);
    gld_lds16(Vt + vbase + (size_t)row * 2048 + sg * 8, &vs[G * 8]);
  }
  asm volatile("s_waitcnt vmcnt(0)" ::: "memory");
  __syncthreads();

  const int fr = lane & 15, gh = lane >> 4;
  const int arow = w * 16 + fr;   // this wave's A rows (q)

  // ---- QK^T: S[16q][64k] per wave
  s16x8 aq[2], bk[2][4];
  #pragma unroll
  for (int ks = 0; ks < 2; ++ks) {
    aq[ks] = *(const s16x8*)&qs[arow * 64 + (((ks * 4 + gh) ^ (arow & 7)) << 3)];
    #pragma unroll
    for (int nt = 0; nt < 4; ++nt) {
      const int krow = nt * 16 + fr;
      bk[ks][nt] = *(const s16x8*)&ks2[krow * 64 + (((ks * 4 + gh) ^ (krow & 7)) << 3)];
    }
  }
  f32x4 s[4] = {};
  #pragma unroll
  for (int ks = 0; ks < 2; ++ks)
    #pragma unroll
    for (int nt = 0; nt < 4; ++nt)
      s[nt] = MFMA16(aq[ks], bk[ks][nt], s[nt]);

  // ---- softmax: D row q = gh*4+j, col k = nt*16+fr -> reduce over fr's 16 lanes
  #pragma unroll
  for (int j = 0; j < 4; ++j) {
    float t0 = s[0][j] * 0.125f, t1 = s[1][j] * 0.125f;
    float t2 = s[2][j] * 0.125f, t3 = s[3][j] * 0.125f;
    float m = fmaxf(fmaxf(t0, t1), fmaxf(t2, t3));
    m = fmaxf(m, __shfl_xor(m, 1, 64));
    m = fmaxf(m, __shfl_xor(m, 2, 64));
    m = fmaxf(m, __shfl_xor(m, 4, 64));
    m = fmaxf(m, __shfl_xor(m, 8, 64));
    t0 = __expf(t0 - m); t1 = __expf(t1 - m);
    t2 = __expf(t2 - m); t3 = __expf(t3 - m);
    float sum = t0 + t1 + t2 + t3;
    sum += __shfl_xor(sum, 1, 64);
    sum += __shfl_xor(sum, 2, 64);
    sum += __shfl_xor(sum, 4, 64);
    sum += __shfl_xor(sum, 8, 64);
    const float r = 1.0f / sum;
    s[0][j] = t0 * r; s[1][j] = t1 * r; s[2][j] = t2 * r; s[3][j] = t3 * r;
  }

  // ---- P -> bf16 LDS (swizzled); wave writes/reads only its own 16 rows
  #pragma unroll
  for (int j = 0; j < 4; ++j) {
    const int q = w * 16 + gh * 4 + j;
    #pragma unroll
    for (int nt = 0; nt < 4; ++nt) {
      const int k = nt * 16 + fr;
      ps[q * 64 + (((k >> 3) ^ (q & 7)) << 3) + (k & 7)] = f2bf(s[nt][j]);
    }
  }

  // ---- PV: X[16q][64d] = P rows x V^T rows
  s16x8 ap[2], bv2[2][4];
  #pragma unroll
  for (int ks = 0; ks < 2; ++ks) {
    ap[ks] = *(const s16x8*)&ps[arow * 64 + (((ks * 4 + gh) ^ (arow & 7)) << 3)];
    #pragma unroll
    for (int nt = 0; nt < 4; ++nt) {
      const int drow = nt * 16 + fr;
      bv2[ks][nt] = *(const s16x8*)&vs[drow * 64 + (((ks * 4 + gh) ^ (drow & 7)) << 3)];
    }
  }
  f32x4 x[4] = {};
  #pragma unroll
  for (int ks = 0; ks < 2; ++ks)
    #pragma unroll
    for (int nt = 0; nt < 4; ++nt)
      x[nt] = MFMA16(ap[ks], bv2[ks][nt], x[nt]);

  // ---- write X: [b*2048 + s][h*64 + d] bf16
  const int b = hb >> 4, h = hb & 15;
  #pragma unroll
  for (int nt = 0; nt < 4; ++nt)
    #pragma unroll
    for (int j = 0; j < 4; ++j) {
      const int sgl = qb * 64 + w * 16 + gh * 4 + j;
      X[((size_t)(b * 2048 + sgl)) * 1024 + h * 64 + nt * 16 + fr] = f2bf(x[nt][j]);
    }
}

// ---------- launch ----------
extern "C" void kernel_launch(void* const* d_in, const int* in_sizes, int n_in,
                              void* d_out, int out_size, void* d_ws, size_t ws_size,
                              hipStream_t stream) {
  const float* query = (const float*)d_in[0];
  const float* key   = (const float*)d_in[1];
  const float* value = (const float*)d_in[2];
  const float* Wq = (const float*)d_in[3]; const float* bq = (const float*)d_in[4];
  const float* Wk = (const float*)d_in[5]; const float* bk = (const float*)d_in[6];
  const float* Wv = (const float*)d_in[7]; const float* bv = (const float*)d_in[8];
  const float* Wo = (const float*)d_in[9]; const float* bo = (const float*)d_in[10];
  float* out = (float*)d_out;

  const size_t W_E = 1024 * 1024;
  const size_t X_E = 4096 * 1024;
  unsigned char* p = (unsigned char*)d_ws;
  auto take = [&](size_t bytes) { void* r = (void*)p; p += bytes; return r; };

  unsigned short* wtq = (unsigned short*)take(W_E * 2);
  unsigned short* wtk = (unsigned short*)take(W_E * 2);
  unsigned short* wtv = (unsigned short*)take(W_E * 2);
  unsigned short* wto = (unsigned short*)take(W_E * 2);
  unsigned short* xq = (unsigned short*)take(X_E * 2);
  unsigned short* xk = (unsigned short*)take(X_E * 2);
  unsigned short* xv = (unsigned short*)take(X_E * 2);
  unsigned short* Qb = (unsigned short*)take(X_E * 2);
  unsigned short* Kb = (unsigned short*)take(X_E * 2);
  unsigned short* Vt = (unsigned short*)take(X_E * 2);
  unsigned short* ao = (unsigned short*)take(X_E * 2);
  (void)ws_size; (void)in_sizes; (void)n_in; (void)out_size;

  transw<<<dim3(256, 4), 256, 0, stream>>>(Wq, wtq, Wk, wtk, Wv, wtv, Wo, wto);
  convert_x3<<<dim3(4096, 3), 256, 0, stream>>>(query, xq, key, xk, value, xv);

  QkvArgs qkv = {};
  qkv.A[0] = xq; qkv.B[0] = wtq; qkv.bias[0] = bq; qkv.out[0] = Qb;
  qkv.A[1] = xk; qkv.B[1] = wtk; qkv.bias[1] = bk; qkv.out[1] = Kb;
  qkv.A[2] = xv; qkv.B[2] = wtv; qkv.bias[2] = bv; qkv.out[2] = Vt;
  gemm_qkv<<<dim3(192), 512, 0, stream>>>(qkv);

  attn_mfma<<<dim3(1024), 256, 0, stream>>>(Qb, Kb, Vt, ao);

  gemm_oproj<<<dim3(256), 256, 0, stream>>>(ao, wto, bo, out);
}